// Round 20
// baseline (1152.433 us; speedup 1.0000x reference)
//
#include <hip/hip_runtime.h>
#include <hip/hip_bf16.h>

typedef __hip_bfloat16 bf16;
typedef unsigned short us;
typedef short short8v __attribute__((ext_vector_type(8)));
typedef float f32x4 __attribute__((ext_vector_type(4)));
typedef __attribute__((address_space(3))) unsigned int lds_u32;
typedef __attribute__((address_space(1))) const unsigned int glb_u32;

#define GLOAD16(gp, lp) __builtin_amdgcn_global_load_lds((glb_u32*)(gp), (lds_u32*)(lp), 16, 0, 0)

#define Bz 4
#define Tz 2048
#define Dz 1024
#define Hz 8
#define DKz 96
#define DVz 192
#define KDz 768
#define VDz 1536
#define Iz 4096
#define BTz (Bz*Tz)

static __device__ __forceinline__ float us2f(us s){
  return __uint_as_float(((unsigned)s) << 16);
}
static __device__ __forceinline__ us f2bs(float f){
  bf16 t = __float2bfloat16(f);
  return *(us*)&t;
}
static __device__ __forceinline__ float sigmoidf_(float x){ return 1.f/(1.f+expf(-x)); }
static __device__ __forceinline__ float siluf_(float x){ return x*sigmoidf_(x); }

// DPP lane-group sums (VALU pipe, no DS):
#define DPPADD(x, ctrl) \
  ((x) + __int_as_float(__builtin_amdgcn_update_dpp(0, __float_as_int(x), (ctrl), 0xF, 0xF, true)))
static __device__ __forceinline__ float gsum16(float x){
  x = DPPADD(x, 0xB1);   // quad_perm [1,0,3,2] : + lane^1
  x = DPPADD(x, 0x4E);   // quad_perm [2,3,0,1] : + lane^2
  x = DPPADD(x, 0x141);  // row_half_mirror     : + other quad (8-group sum)
  x = DPPADD(x, 0x140);  // row_mirror          : + other 8-half (16-group sum)
  return x;
}

// ---------------- merged weight prep: 8 segments of W[K,N] f32 -> WT[N,K] bf16 -------
// Segment tiles (K/32 * N/32): Wo 1536, Wgate 4096, Wup 4096, Wdown 4096,
// Wq 768, Wk 768, Wv 1536, Wg 1536  => 18432 blocks total.
__global__ __launch_bounds__(256) void wprep_all_kernel(
    const float* __restrict__ s0, const float* __restrict__ s1,
    const float* __restrict__ s2, const float* __restrict__ s3,
    const float* __restrict__ s4, const float* __restrict__ s5,
    const float* __restrict__ s6, const float* __restrict__ s7,
    us* __restrict__ d0, us* __restrict__ d1, us* __restrict__ d2,
    us* __restrict__ d3, us* __restrict__ d4, us* __restrict__ d5,
    us* __restrict__ d6, us* __restrict__ d7)
{
  const int NT[8] = {1536,4096,4096,4096,768,768,1536,1536};
  const int KS[8] = {1536,1024,1024,4096,1024,1024,1024,1024};
  const int NS[8] = {1024,4096,4096,1024,768,768,1536,1536};
  int b = blockIdx.x, seg = 0;
  #pragma unroll
  for (int i=0;i<7;i++){ if (b >= NT[seg]){ b -= NT[seg]; seg++; } }
  const float* src = seg==0?s0: seg==1?s1: seg==2?s2: seg==3?s3:
                     seg==4?s4: seg==5?s5: seg==6?s6: s7;
  us* dst = seg==0?d0: seg==1?d1: seg==2?d2: seg==3?d3:
            seg==4?d4: seg==5?d5: seg==6?d6: d7;
  const int K = KS[seg], N = NS[seg];
  const int ktiles = K >> 5;
  const int k0 = (b % ktiles)*32, n0 = (b / ktiles)*32;

  __shared__ float t[32][33];
  const int c = threadIdx.x & 31, r8 = threadIdx.x >> 5;
  #pragma unroll
  for (int i=0;i<4;i++){
    const int r = r8 + i*8;
    t[r][c] = src[(size_t)(k0+r)*N + n0 + c];
  }
  __syncthreads();
  #pragma unroll
  for (int i=0;i<4;i++){
    const int r = r8 + i*8;
    dst[(size_t)(n0+r)*K + k0 + c] = f2bs(t[c][r]);
  }
}

// ---------------- RMSNorm (f32 in -> bf16 out, f32 weights) ----------------
__global__ __launch_bounds__(256) void rmsnorm_kernel(
    const float* __restrict__ x, const float* __restrict__ w, bf16* __restrict__ out)
{
  const int row = blockIdx.x;
  const float* xr = x + (size_t)row*Dz;
  const int i0 = threadIdx.x*4;
  float4 xv = *(const float4*)(xr + i0);
  float ss = xv.x*xv.x+xv.y*xv.y+xv.z*xv.z+xv.w*xv.w;
  #pragma unroll
  for (int off=32; off>=1; off>>=1) ss += __shfl_xor(ss, off);
  __shared__ float red[4];
  if ((threadIdx.x&63)==0) red[threadIdx.x>>6] = ss;
  __syncthreads();
  ss = red[0]+red[1]+red[2]+red[3];
  const float inv = rsqrtf(ss*(1.f/Dz) + 1e-6f);
  float4 wv = *(const float4*)(w + i0);
  ushort4 ov;
  ov.x=f2bs(xv.x*inv*wv.x); ov.y=f2bs(xv.y*inv*wv.y);
  ov.z=f2bs(xv.z*inv*wv.z); ov.w=f2bs(xv.w*inv*wv.w);
  *(ushort4*)((us*)out + (size_t)row*Dz + i0) = ov;
}

// ------- fused RMSNorm1 + beta/exp(g) projections -------
// Writes h bf16 AND meta = (exp(g), beta) in one pass over the row.
__global__ __launch_bounds__(256) void rmsnorm_beta_kernel(
    const float* __restrict__ x, const float* __restrict__ w,
    const float* __restrict__ Wb, const float* __restrict__ Wa,
    const float* __restrict__ A_log, const float* __restrict__ dt_bias,
    bf16* __restrict__ out, float2* __restrict__ meta)
{
  const int row = blockIdx.x;
  const float* xr = x + (size_t)row*Dz;
  const int i0 = threadIdx.x*4;
  float4 xv = *(const float4*)(xr + i0);
  float ss = xv.x*xv.x+xv.y*xv.y+xv.z*xv.z+xv.w*xv.w;
  #pragma unroll
  for (int off=32; off>=1; off>>=1) ss += __shfl_xor(ss, off);
  __shared__ float red1[4];
  if ((threadIdx.x&63)==0) red1[threadIdx.x>>6] = ss;
  __syncthreads();
  ss = red1[0]+red1[1]+red1[2]+red1[3];
  const float inv = rsqrtf(ss*(1.f/Dz) + 1e-6f);
  float4 wv = *(const float4*)(w + i0);
  ushort4 ov;
  ov.x=f2bs(xv.x*inv*wv.x); ov.y=f2bs(xv.y*inv*wv.y);
  ov.z=f2bs(xv.z*inv*wv.z); ov.w=f2bs(xv.w*inv*wv.w);
  *(ushort4*)((us*)out + (size_t)row*Dz + i0) = ov;
  // beta/g partial dots over this thread's 4 channels (use bf16-rounded h,
  // identical numerics to the former separate beta_g pass)
  const float hv4[4] = { us2f(ov.x), us2f(ov.y), us2f(ov.z), us2f(ov.w) };
  float ab[8]={0,0,0,0,0,0,0,0}, aa[8]={0,0,0,0,0,0,0,0};
  #pragma unroll
  for (int tloc=0; tloc<4; tloc++){
    const int kk = i0 + tloc;
    const float hv = hv4[tloc];
    float4 b0 = *(const float4*)(Wb + kk*8);
    float4 b1 = *(const float4*)(Wb + kk*8 + 4);
    float4 a0 = *(const float4*)(Wa + kk*8);
    float4 a1 = *(const float4*)(Wa + kk*8 + 4);
    ab[0]=fmaf(hv,b0.x,ab[0]); ab[1]=fmaf(hv,b0.y,ab[1]);
    ab[2]=fmaf(hv,b0.z,ab[2]); ab[3]=fmaf(hv,b0.w,ab[3]);
    ab[4]=fmaf(hv,b1.x,ab[4]); ab[5]=fmaf(hv,b1.y,ab[5]);
    ab[6]=fmaf(hv,b1.z,ab[6]); ab[7]=fmaf(hv,b1.w,ab[7]);
    aa[0]=fmaf(hv,a0.x,aa[0]); aa[1]=fmaf(hv,a0.y,aa[1]);
    aa[2]=fmaf(hv,a0.z,aa[2]); aa[3]=fmaf(hv,a0.w,aa[3]);
    aa[4]=fmaf(hv,a1.x,aa[4]); aa[5]=fmaf(hv,a1.y,aa[5]);
    aa[6]=fmaf(hv,a1.z,aa[6]); aa[7]=fmaf(hv,a1.w,aa[7]);
  }
  #pragma unroll
  for (int off=32; off>=1; off>>=1){
    #pragma unroll
    for (int n=0;n<8;n++){ ab[n]+=__shfl_xor(ab[n],off); aa[n]+=__shfl_xor(aa[n],off); }
  }
  __shared__ float red2[4][16];
  const int wvv = threadIdx.x>>6, ln = threadIdx.x&63;
  if (ln==0){
    #pragma unroll
    for (int n=0;n<8;n++){ red2[wvv][n]=ab[n]; red2[wvv][8+n]=aa[n]; }
  }
  __syncthreads();
  if (threadIdx.x < 8){
    const int n = threadIdx.x;
    float sb = red2[0][n]+red2[1][n]+red2[2][n]+red2[3][n];
    float sa = red2[0][8+n]+red2[1][8+n]+red2[2][8+n]+red2[3][8+n];
    float xx = sa + dt_bias[n];
    float sp = (xx > 20.f) ? xx : log1pf(expf(xx));
    float eg = expf(-expf(A_log[n])*sp);
    float bt = 1.f/(1.f+expf(-sb));
    meta[(size_t)row*Hz + n] = make_float2(eg, bt);
  }
}

// ------------- MFMA GEMM: C[M,N] = A[M,K](bf16) @ BT[N,K](bf16)^T (+res) -------------
// XCD-aware swizzle: grids must have (gridX*gridY)%8==0 (all call sites satisfy).
// MODE 0: write bf16.  MODE 1: write f32 + f32 residual.
template<int MODE>
__global__ __launch_bounds__(256, 2) void mgemm_kernel(
    const bf16* __restrict__ A, const us* __restrict__ BT,
    const void* __restrict__ res, void* __restrict__ Cout,
    int M, int N, int K)
{
  __shared__ us As[128*64];
  __shared__ us Bs[128*64];
  const int nwgx = gridDim.x;
  const int lid = blockIdx.y*nwgx + blockIdx.x;
  const int cpx = (nwgx*gridDim.y) >> 3;
  const int swz = (lid & 7)*cpx + (lid >> 3);
  const int m0 = (swz / nwgx)*128, n0 = (swz % nwgx)*128;
  const int tid = threadIdx.x;
  const int wid = tid >> 6, lane = tid & 63;
  const int wr = wid >> 1, wc = wid & 1;
  const int fq = lane >> 4, fr = lane & 15;

  const us* Ab = (const us*)A + (size_t)(m0 + (tid>>3))*K + (tid&7)*8;
  const us* Bb = BT + (size_t)(n0 + (tid>>3))*K + (tid&7)*8;
  char* AsB = (char*)As;
  char* BsB = (char*)Bs;
  const int ldsoff = wid*1024;

  f32x4 acc[4][4] = {};
  const int nk = K >> 6;
  for (int kt = 0; kt < nk; ++kt){
    const int kb = kt*64;
    #pragma unroll
    for (int i=0;i<4;i++){
      GLOAD16(Ab + (size_t)(32*i)*K + kb, AsB + ldsoff + i*4096);
      GLOAD16(Bb + (size_t)(32*i)*K + kb, BsB + ldsoff + i*4096);
    }
    __syncthreads();
    #pragma unroll
    for (int ks=0; ks<2; ks++){
      short8v af[4], bf[4];
      #pragma unroll
      for (int r=0;r<4;r++)
        af[r] = *(const short8v*)&As[(wr*64 + r*16 + fr)*64 + ks*32 + fq*8];
      #pragma unroll
      for (int c=0;c<4;c++)
        bf[c] = *(const short8v*)&Bs[(wc*64 + c*16 + fr)*64 + ks*32 + fq*8];
      #pragma unroll
      for (int r=0;r<4;r++)
        #pragma unroll
        for (int c=0;c<4;c++)
          acc[r][c] = __builtin_amdgcn_mfma_f32_16x16x32_bf16(af[r], bf[c], acc[r][c], 0, 0, 0);
    }
    __syncthreads();
  }
  #pragma unroll
  for (int r=0;r<4;r++){
    #pragma unroll
    for (int c=0;c<4;c++){
      const int col = n0 + wc*64 + c*16 + fr;
      #pragma unroll
      for (int jj=0;jj<4;jj++){
        const int row = m0 + wr*64 + r*16 + fq*4 + jj;
        const size_t idx = (size_t)row*N + col;
        const float a = acc[r][c][jj];
        if (MODE==0){
          ((us*)Cout)[idx] = f2bs(a);
        } else {
          ((float*)Cout)[idx] = a + ((const float*)res)[idx];
        }
      }
    }
  }
}

// ------- merged QKVG projection GEMM: A[M,1024] @ qkvgT[4608,1024]^T -------
__global__ __launch_bounds__(256, 2) void proj_gemm_kernel(
    const bf16* __restrict__ A, const us* __restrict__ BT,
    us* __restrict__ preq, us* __restrict__ prek,
    us* __restrict__ prev, us* __restrict__ gout,
    int M, int N, int K)
{
  __shared__ us As[128*64];
  __shared__ us Bs[128*64];
  const int nwgx = gridDim.x;
  const int lid = blockIdx.y*nwgx + blockIdx.x;
  const int cpx = (nwgx*gridDim.y) >> 3;
  const int swz = (lid & 7)*cpx + (lid >> 3);
  const int m0 = (swz / nwgx)*128, n0 = (swz % nwgx)*128;
  const int tid = threadIdx.x;
  const int wid = tid >> 6, lane = tid & 63;
  const int wr = wid >> 1, wc = wid & 1;
  const int fq = lane >> 4, fr = lane & 15;

  const us* Ab = (const us*)A + (size_t)(m0 + (tid>>3))*K + (tid&7)*8;
  const us* Bb = BT + (size_t)(n0 + (tid>>3))*K + (tid&7)*8;
  char* AsB = (char*)As;
  char* BsB = (char*)Bs;
  const int ldsoff = wid*1024;

  f32x4 acc[4][4] = {};
  const int nk = K >> 6;
  for (int kt = 0; kt < nk; ++kt){
    const int kb = kt*64;
    #pragma unroll
    for (int i=0;i<4;i++){
      GLOAD16(Ab + (size_t)(32*i)*K + kb, AsB + ldsoff + i*4096);
      GLOAD16(Bb + (size_t)(32*i)*K + kb, BsB + ldsoff + i*4096);
    }
    __syncthreads();
    #pragma unroll
    for (int ks=0; ks<2; ks++){
      short8v af[4], bf[4];
      #pragma unroll
      for (int r=0;r<4;r++)
        af[r] = *(const short8v*)&As[(wr*64 + r*16 + fr)*64 + ks*32 + fq*8];
      #pragma unroll
      for (int c=0;c<4;c++)
        bf[c] = *(const short8v*)&Bs[(wc*64 + c*16 + fr)*64 + ks*32 + fq*8];
      #pragma unroll
      for (int r=0;r<4;r++)
        #pragma unroll
        for (int c=0;c<4;c++)
          acc[r][c] = __builtin_amdgcn_mfma_f32_16x16x32_bf16(af[r], bf[c], acc[r][c], 0, 0, 0);
    }
    __syncthreads();
  }
  // block-uniform scatter target (col tiles align to 768/1536/3072 boundaries)
  us* dst; int col0, Nout;
  if (n0 < 768)      { dst = preq; col0 = n0;        Nout = 768;  }
  else if (n0 < 1536){ dst = prek; col0 = n0 - 768;  Nout = 768;  }
  else if (n0 < 3072){ dst = prev; col0 = n0 - 1536; Nout = 1536; }
  else               { dst = gout; col0 = n0 - 3072; Nout = 1536; }
  #pragma unroll
  for (int r=0;r<4;r++){
    #pragma unroll
    for (int c=0;c<4;c++){
      const int col = col0 + wc*64 + c*16 + fr;
      #pragma unroll
      for (int jj=0;jj<4;jj++){
        const int row = m0 + wr*64 + r*16 + fq*4 + jj;
        dst[(size_t)row*Nout + col] = f2bs(acc[r][c][jj]);
      }
    }
  }
}

// ------- fused dual GEMM: out = silu(A@Wg^T) * (A@Wu^T), bf16 -------
__global__ __launch_bounds__(256, 2) void mgemm_dual_kernel(
    const bf16* __restrict__ A, const us* __restrict__ BT1, const us* __restrict__ BT2,
    us* __restrict__ Cout, int M, int N, int K)
{
  __shared__ us As[128*64];
  __shared__ us Bs1[128*64];
  __shared__ us Bs2[128*64];
  const int nwgx = gridDim.x;
  const int lid = blockIdx.y*nwgx + blockIdx.x;
  const int cpx = (nwgx*gridDim.y) >> 3;
  const int swz = (lid & 7)*cpx + (lid >> 3);
  const int m0 = (swz / nwgx)*128, n0 = (swz % nwgx)*128;
  const int tid = threadIdx.x;
  const int wid = tid >> 6, lane = tid & 63;
  const int wr = wid >> 1, wc = wid & 1;
  const int fq = lane >> 4, fr = lane & 15;

  const us* Ab  = (const us*)A + (size_t)(m0 + (tid>>3))*K + (tid&7)*8;
  const us* Bb1 = BT1 + (size_t)(n0 + (tid>>3))*K + (tid&7)*8;
  const us* Bb2 = BT2 + (size_t)(n0 + (tid>>3))*K + (tid&7)*8;
  char* AsB  = (char*)As;
  char* BsB1 = (char*)Bs1;
  char* BsB2 = (char*)Bs2;
  const int ldsoff = wid*1024;

  f32x4 acc1[4][4] = {};
  f32x4 acc2[4][4] = {};
  const int nk = K >> 6;
  for (int kt = 0; kt < nk; ++kt){
    const int kb = kt*64;
    #pragma unroll
    for (int i=0;i<4;i++){
      GLOAD16(Ab  + (size_t)(32*i)*K + kb, AsB  + ldsoff + i*4096);
      GLOAD16(Bb1 + (size_t)(32*i)*K + kb, BsB1 + ldsoff + i*4096);
      GLOAD16(Bb2 + (size_t)(32*i)*K + kb, BsB2 + ldsoff + i*4096);
    }
    __syncthreads();
    #pragma unroll
    for (int ks=0; ks<2; ks++){
      short8v af[4], bf1[4], bf2[4];
      #pragma unroll
      for (int r=0;r<4;r++)
        af[r] = *(const short8v*)&As[(wr*64 + r*16 + fr)*64 + ks*32 + fq*8];
      #pragma unroll
      for (int c=0;c<4;c++){
        bf1[c] = *(const short8v*)&Bs1[(wc*64 + c*16 + fr)*64 + ks*32 + fq*8];
        bf2[c] = *(const short8v*)&Bs2[(wc*64 + c*16 + fr)*64 + ks*32 + fq*8];
      }
      #pragma unroll
      for (int r=0;r<4;r++)
        #pragma unroll
        for (int c=0;c<4;c++){
          acc1[r][c] = __builtin_amdgcn_mfma_f32_16x16x32_bf16(af[r], bf1[c], acc1[r][c], 0, 0, 0);
          acc2[r][c] = __builtin_amdgcn_mfma_f32_16x16x32_bf16(af[r], bf2[c], acc2[r][c], 0, 0, 0);
        }
    }
    __syncthreads();
  }
  #pragma unroll
  for (int r=0;r<4;r++){
    #pragma unroll
    for (int c=0;c<4;c++){
      const int col = n0 + wc*64 + c*16 + fr;
      #pragma unroll
      for (int jj=0;jj<4;jj++){
        const int row = m0 + wr*64 + r*16 + fq*4 + jj;
        Cout[(size_t)row*N + col] = f2bs(siluf_(acc1[r][c][jj]) * acc2[r][c][jj]);
      }
    }
  }
}

// ------- fused conv(K=4)+SiLU+l2norm+scale for k,q -> kqn[bt][h][96k|96q] bf16 -------
__global__ __launch_bounds__(64) void conv_kq_kernel(
    const bf16* __restrict__ preq, const bf16* __restrict__ prek,
    const float* __restrict__ wqc, const float* __restrict__ wkc,
    us* __restrict__ kqn)
{
  const int idx = blockIdx.x; const int h = idx & 7; const int bt = idx >> 3;
  const int t = bt & (Tz-1);
  const int lane = threadIdx.x;
  const us* Q = (const us*)preq;
  const us* K = (const us*)prek;
  const int c0 = h*DKz + lane, c1 = c0 + 64;
  const bool hi = lane < 32;
  float yq0=0.f, yq1=0.f, yk0=0.f, yk1=0.f;
  #pragma unroll
  for (int i=0;i<4;i++){
    const int ti = t - 3 + i;
    if (ti >= 0){
      const size_t rowb = (size_t)(bt-3+i)*KDz;
      yq0 = fmaf(us2f(Q[rowb + c0]), wqc[c0*4+i], yq0);
      yk0 = fmaf(us2f(K[rowb + c0]), wkc[c0*4+i], yk0);
      if (hi){
        yq1 = fmaf(us2f(Q[rowb + c1]), wqc[c1*4+i], yq1);
        yk1 = fmaf(us2f(K[rowb + c1]), wkc[c1*4+i], yk1);
      }
    }
  }
  yq0 = siluf_(yq0); yk0 = siluf_(yk0);
  yq1 = hi ? siluf_(yq1) : 0.f;
  yk1 = hi ? siluf_(yk1) : 0.f;
  float ssq = yq0*yq0 + yq1*yq1;
  float ssk = yk0*yk0 + yk1*yk1;
  #pragma unroll
  for (int off=32; off>=1; off>>=1){ ssq += __shfl_xor(ssq,off); ssk += __shfl_xor(ssk,off); }
  const float iq = rsqrtf(ssq + 1e-6f) * 0.10206207262f;  // invq * dk^-0.5
  const float ik = rsqrtf(ssk + 1e-6f);
  const size_t base = (size_t)bt*1536 + (size_t)h*192;
  kqn[base + lane]      = f2bs(yk0*ik);
  kqn[base + 96 + lane] = f2bs(yq0*iq);
  if (hi){
    kqn[base + 64 + lane]      = f2bs(yk1*ik);
    kqn[base + 96 + 64 + lane] = f2bs(yq1*iq);
  }
}

// ------- apply conv+SiLU to v -> vn bf16 -------
__global__ __launch_bounds__(256) void conv_apply_v_kernel(
    const bf16* __restrict__ prev, const float* __restrict__ wvc, bf16* __restrict__ vn)
{
  const int bt = blockIdx.y; const int ccol = blockIdx.x*256 + threadIdx.x;
  const int t = bt & (Tz-1);
  const us* X = (const us*)prev;
  float acc = 0.f;
  #pragma unroll
  for (int i=0;i<4;i++){
    const int ti = t - 3 + i;
    if (ti >= 0) acc = fmaf(us2f(X[(size_t)(bt-3+i)*VDz + ccol]), wvc[ccol*4+i], acc);
  }
  ((us*)vn)[(size_t)bt*VDz + ccol] = f2bs(siluf_(acc));
}

// ---------------- gated delta-rule scan, consume-only, 16-way split ----------------
// Grid = Bz*Hz*16; block (bh, sp) owns v-cols [sp*12, sp*12+12).
// 192 threads: tid = j*16 + g; thread owns S[g*6 .. g*6+5][col sp*12+j].
// 2 blocks/CU -> 6 waves/CU for stall overlap.
// Phase = 16 steps (barriers halved vs 8-step; prefetch wait amortized 2x).
__global__ __launch_bounds__(192, 1) void scan_kernel(
    const us* __restrict__ kqn, const bf16* __restrict__ vn,
    const float2* __restrict__ meta, bf16* __restrict__ o)
{
  const int blk = blockIdx.x;
  const int bh = blk >> 4, sp = blk & 15;
  const int b = bh >> 3, h = bh & 7;
  const int tid = threadIdx.x;
  const int g = tid & 15;
  const int j = tid >> 4;               // 0..11
  const int vc = h*DVz + sp*12 + j;

  __shared__ float kq[2][16][192];      // [buf][step][96 k | 96 q]

  const us* KQ = kqn + (size_t)b*Tz*1536 + h*192 + tid;
  const us* VP = (const us*)vn + (size_t)b*Tz*VDz + vc;
  us* op = (us*)o + (size_t)b*Tz*VDz + vc;
  const float2* MP = meta + (size_t)b*Tz*Hz + h;

  float S[6];
  #pragma unroll
  for (int m=0;m<6;m++) S[m]=0.f;

  float ced[16], egb[16], cvb[16];   // eg, eg*beta, v*beta

  // ---- prologue: stage phase 0 ----
  #pragma unroll
  for (int s=0;s<16;s++){
    kq[0][s][tid] = us2f(KQ[(size_t)s*1536]);
    const float cv = us2f(VP[(size_t)s*VDz]);
    const float2 m = MP[(size_t)s*Hz];
    ced[s] = m.x; egb[s] = m.x*m.y; cvb[s] = cv*m.y;
  }
  __syncthreads();

  for (int ph=0; ph<Tz/16; ph++){
    const int base = ph*16;
    const int p = ph & 1;
    const bool more = (base + 16 < Tz);
    const int nb = more ? base + 16 : base;   // clamp; values unused when !more
    // (1) prefetch next-phase inputs (independent -> issue at top)
    float nkq[16], nv[16]; float2 nm[16];
    #pragma unroll
    for (int s=0;s<16;s++){
      nkq[s] = us2f(KQ[(size_t)(nb+s)*1536]);
      nv[s]  = us2f(VP[(size_t)(nb+s)*VDz]);
      nm[s]  = MP[(size_t)(nb+s)*Hz];
    }
    // (2) consume 16 steps; parity register sets, b64 reads (g*24B: all-banks-once)
    float2 kf[2][3], qf[2][3];
    #pragma unroll
    for (int m=0;m<3;m++){
      kf[0][m] = *(const float2*)&kq[p][0][g*6 + m*2];
      qf[0][m] = *(const float2*)&kq[p][0][96 + g*6 + m*2];
    }
    #pragma unroll
    for (int s=0;s<16;s++){
      const int cu = s & 1, nx = cu ^ 1;
      if (s < 15){
        #pragma unroll
        for (int m=0;m<3;m++){
          kf[nx][m] = *(const float2*)&kq[p][s+1][g*6 + m*2];
          qf[nx][m] = *(const float2*)&kq[p][s+1][96 + g*6 + m*2];
        }
      }
      float a0, a1;
      a0 = kf[cu][0].x*S[0];          a1 = kf[cu][0].y*S[1];
      a0 = fmaf(kf[cu][1].x,S[2],a0); a1 = fmaf(kf[cu][1].y,S[3],a1);
      a0 = fmaf(kf[cu][2].x,S[4],a0); a1 = fmaf(kf[cu][2].y,S[5],a1);
      const float pv = gsum16(a0+a1);
      const float eg = ced[s];
      const float delta = fmaf(-egb[s], pv, cvb[s]);   // (cv - eg*pv)*beta
      float o0, o1, t0;
      t0 = fmaf(eg,S[0], kf[cu][0].x*delta); S[0]=t0; o0 = qf[cu][0].x*t0;
      t0 = fmaf(eg,S[1], kf[cu][0].y*delta); S[1]=t0; o1 = qf[cu][0].y*t0;
      t0 = fmaf(eg,S[2], kf[cu][1].x*delta); S[2]=t0; o0 = fmaf(qf[cu][1].x,t0,o0);
      t0 = fmaf(eg,S[3], kf[cu][1].y*delta); S[3]=t0; o1 = fmaf(qf[cu][1].y,t0,o1);
      t0 = fmaf(eg,S[4], kf[cu][2].x*delta); S[4]=t0; o0 = fmaf(qf[cu][2].x,t0,o0);
      t0 = fmaf(eg,S[5], kf[cu][2].y*delta); S[5]=t0; o1 = fmaf(qf[cu][2].y,t0,o1);
      const float po = gsum16(o0+o1);
      if (g == 0) op[(size_t)(base+s)*VDz] = f2bs(po);
    }
    // (3) stage next phase from prefetched registers (1:1, branch-free)
    if (more){
      #pragma unroll
      for (int s=0;s<16;s++){
        kq[p^1][s][tid] = nkq[s];
        ced[s] = nm[s].x; egb[s] = nm[s].x*nm[s].y; cvb[s] = nv[s]*nm[s].y;
      }
    }
    __syncthreads();
  }
}

// ---------------- output gate: rmsnorm_dv(o) * silu(gout) ----------------
__global__ __launch_bounds__(64) void gate_out_kernel(
    const bf16* __restrict__ o, const bf16* __restrict__ gout,
    const float* __restrict__ onw, bf16* __restrict__ og)
{
  const size_t base = (size_t)blockIdx.x * DVz;
  const int lane = threadIdx.x;
  const us* O = (const us*)o;
  float x0 = us2f(O[base+lane]), x1 = us2f(O[base+64+lane]), x2 = us2f(O[base+128+lane]);
  float ss = x0*x0 + x1*x1 + x2*x2;
  #pragma unroll
  for (int off=32; off>=1; off>>=1) ss += __shfl_xor(ss, off);
  const float inv = rsqrtf(ss*(1.f/DVz) + 1e-6f);
  const us* G = (const us*)gout;
  us* OG = (us*)og;
  float xs[3] = {x0, x1, x2};
  #pragma unroll
  for (int i=0;i<3;i++){
    const int c = lane + 64*i;
    const float gv = us2f(G[base+c]);
    OG[base+c] = f2bs(xs[i]*inv*onw[c] * siluf_(gv));
  }
}

extern "C" void kernel_launch(void* const* d_in, const int* in_sizes, int n_in,
                              void* d_out, int out_size, void* d_ws, size_t ws_size,
                              hipStream_t stream) {
  const float* x        = (const float*)d_in[0];
  const float* Wq       = (const float*)d_in[1];
  const float* Wk       = (const float*)d_in[2];
  const float* Wv       = (const float*)d_in[3];
  const float* Wb       = (const float*)d_in[4];
  const float* Wa       = (const float*)d_in[5];
  const float* A_log    = (const float*)d_in[6];
  const float* dt_bias  = (const float*)d_in[7];
  const float* conv_q_w = (const float*)d_in[8];
  const float* conv_k_w = (const float*)d_in[9];
  const float* conv_v_w = (const float*)d_in[10];
  const float* Wg       = (const float*)d_in[11];
  const float* onorm_w  = (const float*)d_in[12];
  const float* Wo       = (const float*)d_in[13];
  const float* norm1_w  = (const float*)d_in[14];
  const float* norm2_w  = (const float*)d_in[15];
  const float* Wgate    = (const float*)d_in[16];
  const float* Wup      = (const float*)d_in[17];
  const float* Wdown    = (const float*)d_in[18];

  char* W = (char*)d_ws;
  // bf16-transposed weights (rewritten every launch; deterministic)
  us* WoT    = (us*)(W + 0);           // live thru Wo GEMM
  us* WgateT = (us*)(W + 3145728);     // live thru MLP
  us* WupT   = (us*)(W + 11534336);
  us* WdownT = (us*)(W + 19922944);    // ends 28,311,552
  // concatenated qkvg^T [4608,1024] bf16 (q rows 0-767, k 768-1535, v 1536-3071,
  // g 3072-4607); dead after proj GEMM
  us* WqkvgT = (us*)(W + 28311552);    // ends 37,748,736
  // activations
  bf16*   h_   = (bf16*)  (W + 37748736);   // [8192,1024]; dead after proj GEMM
  bf16*   preq = (bf16*)  (W + 54525952);   // [8192,768];  dead after conv_kq
  bf16*   prek = (bf16*)  (W + 67108864);   // [8192,768];  dead after conv_kq
  bf16*   prev = (bf16*)  (W + 79691776);   // [8192,1536]; dead after conv_apply_v
  float2* meta = (float2*)(W + 104857600);  // [8192,8] float2; dead after scan
  bf16*   gout = (bf16*)  (W + 105906176);  // [8192,1536]; ends 131,072,000 (PEAK)
  // aliases over dead regions
  us*    kqn   = (us*)   (W + 28311552);   // [8192,1536] bf16 over WqkvgT+h_-head (dead after scan)
  bf16*  vn    = (bf16*) (W + 54525952);   // [8192,1536] over preq+prek (dead after scan)
  bf16*  o_    = (bf16*) (W + 79691776);   // [8192,1536] over prev (dead after gate_out)
  float* x2    = (float*)(W + 79691776);   // [8192,1024] f32 over o_+meta+gout-head (post gate_out)
  bf16*  og    = (bf16*) (W + 28311552);   // [8192,1536] over kqn (dead after Wo GEMM)
  bf16*  h2    = (bf16*) (W + 113246208);  // [8192,1024] over gout tail (dead after gate_out)
  bf16*  gateC = (bf16*) (W + 28311552);   // [4096,4096] over og+vn region (dead after Wo GEMM)

  // 0. weight prep (transpose + f32->bf16), single merged launch (18432 tiles)
  wprep_all_kernel<<<18432, 256, 0, stream>>>(
      Wo, Wgate, Wup, Wdown, Wq, Wk, Wv, Wg,
      WoT, WgateT, WupT, WdownT,
      WqkvgT, WqkvgT + 768*1024, WqkvgT + 1536*1024, WqkvgT + 3072*1024);
  // 1. pre-norm fused with beta/eg projections
  rmsnorm_beta_kernel<<<BTz, 256, 0, stream>>>(x, norm1_w, Wb, Wa, A_log, dt_bias,
                                               h_, meta);
  // 2. merged q/k/v/g projection (one GEMM, scatter epilogue)
  proj_gemm_kernel<<<dim3(36,64), 256, 0, stream>>>(h_, WqkvgT,
      (us*)preq, (us*)prek, (us*)prev, (us*)gout, BTz, 4608, Dz);
  // 3. fused conv+silu+l2+scale -> kqn; conv+silu -> vn; consume-only scan
  conv_kq_kernel<<<BTz*Hz, 64, 0, stream>>>(preq, prek, conv_q_w, conv_k_w, kqn);
  conv_apply_v_kernel<<<dim3(6, BTz), 256, 0, stream>>>(prev, conv_v_w, vn);
  scan_kernel<<<Bz*Hz*16, 192, 0, stream>>>(kqn, vn, meta, o_);
  // 4. output gating + Wo projection with residual
  gate_out_kernel<<<BTz*Hz, 64, 0, stream>>>(o_, gout, onorm_w, og);
  mgemm_kernel<1><<<dim3(8,64), 256, 0, stream>>>(og, WoT, x, x2, BTz, Dz, VDz);
  // 5. MLP, chunked over 2 x 4096 rows; gate&up fused into one dual GEMM
  rmsnorm_kernel<<<BTz, 256, 0, stream>>>(x2, norm2_w, h2);
  for (int c = 0; c < 2; c++){
    const bf16*  h2c = h2 + (size_t)c*4096*Dz;
    const float* x2c = x2 + (size_t)c*4096*Dz;
    float*       out = (float*)d_out + (size_t)c*4096*Dz;
    mgemm_dual_kernel<<<dim3(32,32), 256, 0, stream>>>(h2c, WgateT, WupT, (us*)gateC,
                                                       4096, Iz, Dz);
    mgemm_kernel<1><<<dim3(8,32),  256, 0, stream>>>(gateC, WdownT, x2c, out, 4096, Dz, Iz);
  }
}

// Round 21
// 1132.408 us; speedup vs baseline: 1.0177x; 1.0177x over previous
//
#include <hip/hip_runtime.h>
#include <hip/hip_bf16.h>

typedef __hip_bfloat16 bf16;
typedef unsigned short us;
typedef short short8v __attribute__((ext_vector_type(8)));
typedef float f32x4 __attribute__((ext_vector_type(4)));
typedef __attribute__((address_space(3))) unsigned int lds_u32;
typedef __attribute__((address_space(1))) const unsigned int glb_u32;

#define GLOAD16(gp, lp) __builtin_amdgcn_global_load_lds((glb_u32*)(gp), (lds_u32*)(lp), 16, 0, 0)

#define Bz 4
#define Tz 2048
#define Dz 1024
#define Hz 8
#define DKz 96
#define DVz 192
#define KDz 768
#define VDz 1536
#define Iz 4096
#define BTz (Bz*Tz)

static __device__ __forceinline__ float us2f(us s){
  return __uint_as_float(((unsigned)s) << 16);
}
static __device__ __forceinline__ us f2bs(float f){
  bf16 t = __float2bfloat16(f);
  return *(us*)&t;
}
static __device__ __forceinline__ float sigmoidf_(float x){ return 1.f/(1.f+expf(-x)); }
static __device__ __forceinline__ float siluf_(float x){ return x*sigmoidf_(x); }

// DPP lane-group sums (VALU pipe, no DS):
#define DPPADD(x, ctrl) \
  ((x) + __int_as_float(__builtin_amdgcn_update_dpp(0, __float_as_int(x), (ctrl), 0xF, 0xF, true)))
static __device__ __forceinline__ float gsum16(float x){
  x = DPPADD(x, 0xB1);   // quad_perm [1,0,3,2] : + lane^1
  x = DPPADD(x, 0x4E);   // quad_perm [2,3,0,1] : + lane^2
  x = DPPADD(x, 0x141);  // row_half_mirror     : + other quad (8-group sum)
  x = DPPADD(x, 0x140);  // row_mirror          : + other 8-half (16-group sum)
  return x;
}

// ---------------- merged weight prep: 8 segments of W[K,N] f32 -> WT[N,K] bf16 -------
// Segment tiles (K/32 * N/32): Wo 1536, Wgate 4096, Wup 4096, Wdown 4096,
// Wq 768, Wk 768, Wv 1536, Wg 1536  => 18432 blocks total.
__global__ __launch_bounds__(256) void wprep_all_kernel(
    const float* __restrict__ s0, const float* __restrict__ s1,
    const float* __restrict__ s2, const float* __restrict__ s3,
    const float* __restrict__ s4, const float* __restrict__ s5,
    const float* __restrict__ s6, const float* __restrict__ s7,
    us* __restrict__ d0, us* __restrict__ d1, us* __restrict__ d2,
    us* __restrict__ d3, us* __restrict__ d4, us* __restrict__ d5,
    us* __restrict__ d6, us* __restrict__ d7)
{
  const int NT[8] = {1536,4096,4096,4096,768,768,1536,1536};
  const int KS[8] = {1536,1024,1024,4096,1024,1024,1024,1024};
  const int NS[8] = {1024,4096,4096,1024,768,768,1536,1536};
  int b = blockIdx.x, seg = 0;
  #pragma unroll
  for (int i=0;i<7;i++){ if (b >= NT[seg]){ b -= NT[seg]; seg++; } }
  const float* src = seg==0?s0: seg==1?s1: seg==2?s2: seg==3?s3:
                     seg==4?s4: seg==5?s5: seg==6?s6: s7;
  us* dst = seg==0?d0: seg==1?d1: seg==2?d2: seg==3?d3:
            seg==4?d4: seg==5?d5: seg==6?d6: d7;
  const int K = KS[seg], N = NS[seg];
  const int ktiles = K >> 5;
  const int k0 = (b % ktiles)*32, n0 = (b / ktiles)*32;

  __shared__ float t[32][33];
  const int c = threadIdx.x & 31, r8 = threadIdx.x >> 5;
  #pragma unroll
  for (int i=0;i<4;i++){
    const int r = r8 + i*8;
    t[r][c] = src[(size_t)(k0+r)*N + n0 + c];
  }
  __syncthreads();
  #pragma unroll
  for (int i=0;i<4;i++){
    const int r = r8 + i*8;
    dst[(size_t)(n0+r)*K + k0 + c] = f2bs(t[c][r]);
  }
}

// ---------------- RMSNorm (f32 in -> bf16 out, f32 weights) ----------------
__global__ __launch_bounds__(256) void rmsnorm_kernel(
    const float* __restrict__ x, const float* __restrict__ w, bf16* __restrict__ out)
{
  const int row = blockIdx.x;
  const float* xr = x + (size_t)row*Dz;
  const int i0 = threadIdx.x*4;
  float4 xv = *(const float4*)(xr + i0);
  float ss = xv.x*xv.x+xv.y*xv.y+xv.z*xv.z+xv.w*xv.w;
  #pragma unroll
  for (int off=32; off>=1; off>>=1) ss += __shfl_xor(ss, off);
  __shared__ float red[4];
  if ((threadIdx.x&63)==0) red[threadIdx.x>>6] = ss;
  __syncthreads();
  ss = red[0]+red[1]+red[2]+red[3];
  const float inv = rsqrtf(ss*(1.f/Dz) + 1e-6f);
  float4 wv = *(const float4*)(w + i0);
  ushort4 ov;
  ov.x=f2bs(xv.x*inv*wv.x); ov.y=f2bs(xv.y*inv*wv.y);
  ov.z=f2bs(xv.z*inv*wv.z); ov.w=f2bs(xv.w*inv*wv.w);
  *(ushort4*)((us*)out + (size_t)row*Dz + i0) = ov;
}

// ------------- MFMA GEMM: C[M,N] = A[M,K](bf16) @ BT[N,K](bf16)^T (+res) -------------
// XCD-aware swizzle: grids must have (gridX*gridY)%8==0 (all call sites satisfy).
// MODE 0: write bf16.  MODE 1: write f32 + f32 residual.
template<int MODE>
__global__ __launch_bounds__(256, 2) void mgemm_kernel(
    const bf16* __restrict__ A, const us* __restrict__ BT,
    const void* __restrict__ res, void* __restrict__ Cout,
    int M, int N, int K)
{
  __shared__ us As[128*64];
  __shared__ us Bs[128*64];
  const int nwgx = gridDim.x;
  const int lid = blockIdx.y*nwgx + blockIdx.x;
  const int cpx = (nwgx*gridDim.y) >> 3;
  const int swz = (lid & 7)*cpx + (lid >> 3);
  const int m0 = (swz / nwgx)*128, n0 = (swz % nwgx)*128;
  const int tid = threadIdx.x;
  const int wid = tid >> 6, lane = tid & 63;
  const int wr = wid >> 1, wc = wid & 1;
  const int fq = lane >> 4, fr = lane & 15;

  const us* Ab = (const us*)A + (size_t)(m0 + (tid>>3))*K + (tid&7)*8;
  const us* Bb = BT + (size_t)(n0 + (tid>>3))*K + (tid&7)*8;
  char* AsB = (char*)As;
  char* BsB = (char*)Bs;
  const int ldsoff = wid*1024;

  f32x4 acc[4][4] = {};
  const int nk = K >> 6;
  for (int kt = 0; kt < nk; ++kt){
    const int kb = kt*64;
    #pragma unroll
    for (int i=0;i<4;i++){
      GLOAD16(Ab + (size_t)(32*i)*K + kb, AsB + ldsoff + i*4096);
      GLOAD16(Bb + (size_t)(32*i)*K + kb, BsB + ldsoff + i*4096);
    }
    __syncthreads();
    #pragma unroll
    for (int ks=0; ks<2; ks++){
      short8v af[4], bf[4];
      #pragma unroll
      for (int r=0;r<4;r++)
        af[r] = *(const short8v*)&As[(wr*64 + r*16 + fr)*64 + ks*32 + fq*8];
      #pragma unroll
      for (int c=0;c<4;c++)
        bf[c] = *(const short8v*)&Bs[(wc*64 + c*16 + fr)*64 + ks*32 + fq*8];
      #pragma unroll
      for (int r=0;r<4;r++)
        #pragma unroll
        for (int c=0;c<4;c++)
          acc[r][c] = __builtin_amdgcn_mfma_f32_16x16x32_bf16(af[r], bf[c], acc[r][c], 0, 0, 0);
    }
    __syncthreads();
  }
  #pragma unroll
  for (int r=0;r<4;r++){
    #pragma unroll
    for (int c=0;c<4;c++){
      const int col = n0 + wc*64 + c*16 + fr;
      #pragma unroll
      for (int jj=0;jj<4;jj++){
        const int row = m0 + wr*64 + r*16 + fq*4 + jj;
        const size_t idx = (size_t)row*N + col;
        const float a = acc[r][c][jj];
        if (MODE==0){
          ((us*)Cout)[idx] = f2bs(a);
        } else {
          ((float*)Cout)[idx] = a + ((const float*)res)[idx];
        }
      }
    }
  }
}

// ------- merged QKVG projection GEMM: A[M,1024] @ qkvgT[4608,1024]^T -------
__global__ __launch_bounds__(256, 2) void proj_gemm_kernel(
    const bf16* __restrict__ A, const us* __restrict__ BT,
    us* __restrict__ preq, us* __restrict__ prek,
    us* __restrict__ prev, us* __restrict__ gout,
    int M, int N, int K)
{
  __shared__ us As[128*64];
  __shared__ us Bs[128*64];
  const int nwgx = gridDim.x;
  const int lid = blockIdx.y*nwgx + blockIdx.x;
  const int cpx = (nwgx*gridDim.y) >> 3;
  const int swz = (lid & 7)*cpx + (lid >> 3);
  const int m0 = (swz / nwgx)*128, n0 = (swz % nwgx)*128;
  const int tid = threadIdx.x;
  const int wid = tid >> 6, lane = tid & 63;
  const int wr = wid >> 1, wc = wid & 1;
  const int fq = lane >> 4, fr = lane & 15;

  const us* Ab = (const us*)A + (size_t)(m0 + (tid>>3))*K + (tid&7)*8;
  const us* Bb = BT + (size_t)(n0 + (tid>>3))*K + (tid&7)*8;
  char* AsB = (char*)As;
  char* BsB = (char*)Bs;
  const int ldsoff = wid*1024;

  f32x4 acc[4][4] = {};
  const int nk = K >> 6;
  for (int kt = 0; kt < nk; ++kt){
    const int kb = kt*64;
    #pragma unroll
    for (int i=0;i<4;i++){
      GLOAD16(Ab + (size_t)(32*i)*K + kb, AsB + ldsoff + i*4096);
      GLOAD16(Bb + (size_t)(32*i)*K + kb, BsB + ldsoff + i*4096);
    }
    __syncthreads();
    #pragma unroll
    for (int ks=0; ks<2; ks++){
      short8v af[4], bf[4];
      #pragma unroll
      for (int r=0;r<4;r++)
        af[r] = *(const short8v*)&As[(wr*64 + r*16 + fr)*64 + ks*32 + fq*8];
      #pragma unroll
      for (int c=0;c<4;c++)
        bf[c] = *(const short8v*)&Bs[(wc*64 + c*16 + fr)*64 + ks*32 + fq*8];
      #pragma unroll
      for (int r=0;r<4;r++)
        #pragma unroll
        for (int c=0;c<4;c++)
          acc[r][c] = __builtin_amdgcn_mfma_f32_16x16x32_bf16(af[r], bf[c], acc[r][c], 0, 0, 0);
    }
    __syncthreads();
  }
  // block-uniform scatter target (col tiles align to 768/1536/3072 boundaries)
  us* dst; int col0, Nout;
  if (n0 < 768)      { dst = preq; col0 = n0;        Nout = 768;  }
  else if (n0 < 1536){ dst = prek; col0 = n0 - 768;  Nout = 768;  }
  else if (n0 < 3072){ dst = prev; col0 = n0 - 1536; Nout = 1536; }
  else               { dst = gout; col0 = n0 - 3072; Nout = 1536; }
  #pragma unroll
  for (int r=0;r<4;r++){
    #pragma unroll
    for (int c=0;c<4;c++){
      const int col = col0 + wc*64 + c*16 + fr;
      #pragma unroll
      for (int jj=0;jj<4;jj++){
        const int row = m0 + wr*64 + r*16 + fq*4 + jj;
        dst[(size_t)row*Nout + col] = f2bs(acc[r][c][jj]);
      }
    }
  }
}

// ------- fused dual GEMM: out = silu(A@Wg^T) * (A@Wu^T), bf16 -------
__global__ __launch_bounds__(256, 2) void mgemm_dual_kernel(
    const bf16* __restrict__ A, const us* __restrict__ BT1, const us* __restrict__ BT2,
    us* __restrict__ Cout, int M, int N, int K)
{
  __shared__ us As[128*64];
  __shared__ us Bs1[128*64];
  __shared__ us Bs2[128*64];
  const int nwgx = gridDim.x;
  const int lid = blockIdx.y*nwgx + blockIdx.x;
  const int cpx = (nwgx*gridDim.y) >> 3;
  const int swz = (lid & 7)*cpx + (lid >> 3);
  const int m0 = (swz / nwgx)*128, n0 = (swz % nwgx)*128;
  const int tid = threadIdx.x;
  const int wid = tid >> 6, lane = tid & 63;
  const int wr = wid >> 1, wc = wid & 1;
  const int fq = lane >> 4, fr = lane & 15;

  const us* Ab  = (const us*)A + (size_t)(m0 + (tid>>3))*K + (tid&7)*8;
  const us* Bb1 = BT1 + (size_t)(n0 + (tid>>3))*K + (tid&7)*8;
  const us* Bb2 = BT2 + (size_t)(n0 + (tid>>3))*K + (tid&7)*8;
  char* AsB  = (char*)As;
  char* BsB1 = (char*)Bs1;
  char* BsB2 = (char*)Bs2;
  const int ldsoff = wid*1024;

  f32x4 acc1[4][4] = {};
  f32x4 acc2[4][4] = {};
  const int nk = K >> 6;
  for (int kt = 0; kt < nk; ++kt){
    const int kb = kt*64;
    #pragma unroll
    for (int i=0;i<4;i++){
      GLOAD16(Ab  + (size_t)(32*i)*K + kb, AsB  + ldsoff + i*4096);
      GLOAD16(Bb1 + (size_t)(32*i)*K + kb, BsB1 + ldsoff + i*4096);
      GLOAD16(Bb2 + (size_t)(32*i)*K + kb, BsB2 + ldsoff + i*4096);
    }
    __syncthreads();
    #pragma unroll
    for (int ks=0; ks<2; ks++){
      short8v af[4], bf1[4], bf2[4];
      #pragma unroll
      for (int r=0;r<4;r++)
        af[r] = *(const short8v*)&As[(wr*64 + r*16 + fr)*64 + ks*32 + fq*8];
      #pragma unroll
      for (int c=0;c<4;c++){
        bf1[c] = *(const short8v*)&Bs1[(wc*64 + c*16 + fr)*64 + ks*32 + fq*8];
        bf2[c] = *(const short8v*)&Bs2[(wc*64 + c*16 + fr)*64 + ks*32 + fq*8];
      }
      #pragma unroll
      for (int r=0;r<4;r++)
        #pragma unroll
        for (int c=0;c<4;c++){
          acc1[r][c] = __builtin_amdgcn_mfma_f32_16x16x32_bf16(af[r], bf1[c], acc1[r][c], 0, 0, 0);
          acc2[r][c] = __builtin_amdgcn_mfma_f32_16x16x32_bf16(af[r], bf2[c], acc2[r][c], 0, 0, 0);
        }
    }
    __syncthreads();
  }
  #pragma unroll
  for (int r=0;r<4;r++){
    #pragma unroll
    for (int c=0;c<4;c++){
      const int col = n0 + wc*64 + c*16 + fr;
      #pragma unroll
      for (int jj=0;jj<4;jj++){
        const int row = m0 + wr*64 + r*16 + fq*4 + jj;
        Cout[(size_t)row*N + col] = f2bs(siluf_(acc1[r][c][jj]) * acc2[r][c][jj]);
      }
    }
  }
}

// ------- beta / exp(g) projections -> meta = (exp(g), beta) float2 -------
__global__ __launch_bounds__(256) void beta_g_kernel(
    const bf16* __restrict__ hh, const float* __restrict__ Wb, const float* __restrict__ Wa,
    const float* __restrict__ A_log, const float* __restrict__ dt_bias,
    float2* __restrict__ meta)
{
  const int row = blockIdx.x;
  const us* hr = (const us*)hh + (size_t)row*Dz;
  float ab[8]={0,0,0,0,0,0,0,0}, aa[8]={0,0,0,0,0,0,0,0};
  for (int kk=threadIdx.x; kk<Dz; kk+=256){
    const float hv = us2f(hr[kk]);
    float4 b0 = *(const float4*)(Wb + kk*8);
    float4 b1 = *(const float4*)(Wb + kk*8 + 4);
    float4 a0 = *(const float4*)(Wa + kk*8);
    float4 a1 = *(const float4*)(Wa + kk*8 + 4);
    ab[0]=fmaf(hv,b0.x,ab[0]); ab[1]=fmaf(hv,b0.y,ab[1]);
    ab[2]=fmaf(hv,b0.z,ab[2]); ab[3]=fmaf(hv,b0.w,ab[3]);
    ab[4]=fmaf(hv,b1.x,ab[4]); ab[5]=fmaf(hv,b1.y,ab[5]);
    ab[6]=fmaf(hv,b1.z,ab[6]); ab[7]=fmaf(hv,b1.w,ab[7]);
    aa[0]=fmaf(hv,a0.x,aa[0]); aa[1]=fmaf(hv,a0.y,aa[1]);
    aa[2]=fmaf(hv,a0.z,aa[2]); aa[3]=fmaf(hv,a0.w,aa[3]);
    aa[4]=fmaf(hv,a1.x,aa[4]); aa[5]=fmaf(hv,a1.y,aa[5]);
    aa[6]=fmaf(hv,a1.z,aa[6]); aa[7]=fmaf(hv,a1.w,aa[7]);
  }
  #pragma unroll
  for (int off=32; off>=1; off>>=1){
    #pragma unroll
    for (int n=0;n<8;n++){ ab[n]+=__shfl_xor(ab[n],off); aa[n]+=__shfl_xor(aa[n],off); }
  }
  __shared__ float red[4][16];
  const int wv = threadIdx.x>>6, ln = threadIdx.x&63;
  if (ln==0){
    #pragma unroll
    for (int n=0;n<8;n++){ red[wv][n]=ab[n]; red[wv][8+n]=aa[n]; }
  }
  __syncthreads();
  if (threadIdx.x < 8){
    const int n = threadIdx.x;
    float sb = red[0][n]+red[1][n]+red[2][n]+red[3][n];
    float sa = red[0][8+n]+red[1][8+n]+red[2][8+n]+red[3][8+n];
    float xx = sa + dt_bias[n];
    float sp = (xx > 20.f) ? xx : log1pf(expf(xx));
    float eg = expf(-expf(A_log[n])*sp);
    float bt = 1.f/(1.f+expf(-sb));
    meta[(size_t)row*Hz + n] = make_float2(eg, bt);
  }
}

// ------- fused conv(K=4)+SiLU+l2norm+scale for k,q -> kqn[bt][h][96k|96q] bf16 -------
// 256 threads = 4 waves; wave w handles unit (bt,h) = blockIdx.x*4 + w.
__global__ __launch_bounds__(256) void conv_kq_kernel(
    const bf16* __restrict__ preq, const bf16* __restrict__ prek,
    const float* __restrict__ wqc, const float* __restrict__ wkc,
    us* __restrict__ kqn)
{
  const int u = blockIdx.x*4 + (threadIdx.x >> 6);
  const int h = u & 7; const int bt = u >> 3;
  const int t = bt & (Tz-1);
  const int lane = threadIdx.x & 63;
  const us* Q = (const us*)preq;
  const us* K = (const us*)prek;
  const int c0 = h*DKz + lane, c1 = c0 + 64;
  const bool hi = lane < 32;
  float yq0=0.f, yq1=0.f, yk0=0.f, yk1=0.f;
  #pragma unroll
  for (int i=0;i<4;i++){
    const int ti = t - 3 + i;
    if (ti >= 0){
      const size_t rowb = (size_t)(bt-3+i)*KDz;
      yq0 = fmaf(us2f(Q[rowb + c0]), wqc[c0*4+i], yq0);
      yk0 = fmaf(us2f(K[rowb + c0]), wkc[c0*4+i], yk0);
      if (hi){
        yq1 = fmaf(us2f(Q[rowb + c1]), wqc[c1*4+i], yq1);
        yk1 = fmaf(us2f(K[rowb + c1]), wkc[c1*4+i], yk1);
      }
    }
  }
  yq0 = siluf_(yq0); yk0 = siluf_(yk0);
  yq1 = hi ? siluf_(yq1) : 0.f;
  yk1 = hi ? siluf_(yk1) : 0.f;
  float ssq = yq0*yq0 + yq1*yq1;
  float ssk = yk0*yk0 + yk1*yk1;
  #pragma unroll
  for (int off=32; off>=1; off>>=1){ ssq += __shfl_xor(ssq,off); ssk += __shfl_xor(ssk,off); }
  const float iq = rsqrtf(ssq + 1e-6f) * 0.10206207262f;  // invq * dk^-0.5
  const float ik = rsqrtf(ssk + 1e-6f);
  const size_t base = (size_t)bt*1536 + (size_t)h*192;
  kqn[base + lane]      = f2bs(yk0*ik);
  kqn[base + 96 + lane] = f2bs(yq0*iq);
  if (hi){
    kqn[base + 64 + lane]      = f2bs(yk1*ik);
    kqn[base + 96 + 64 + lane] = f2bs(yq1*iq);
  }
}

// ------- apply conv+SiLU to v -> vn bf16 -------
__global__ __launch_bounds__(256) void conv_apply_v_kernel(
    const bf16* __restrict__ prev, const float* __restrict__ wvc, bf16* __restrict__ vn)
{
  const int bt = blockIdx.y; const int ccol = blockIdx.x*256 + threadIdx.x;
  const int t = bt & (Tz-1);
  const us* X = (const us*)prev;
  float acc = 0.f;
  #pragma unroll
  for (int i=0;i<4;i++){
    const int ti = t - 3 + i;
    if (ti >= 0) acc = fmaf(us2f(X[(size_t)(bt-3+i)*VDz + ccol]), wvc[ccol*4+i], acc);
  }
  ((us*)vn)[(size_t)bt*VDz + ccol] = f2bs(siluf_(acc));
}

// ---------------- gated delta-rule scan, consume-only, 16-way split ----------------
// Grid = Bz*Hz*16; block (bh, sp) owns v-cols [sp*12, sp*12+12).
// 192 threads: tid = j*16 + g; thread owns S[g*6 .. g*6+5][col sp*12+j].
// 2 blocks/CU -> 6 waves/CU for stall overlap.
// Phase = 16 steps (barriers halved vs 8-step; prefetch wait amortized 2x).
__global__ __launch_bounds__(192, 1) void scan_kernel(
    const us* __restrict__ kqn, const bf16* __restrict__ vn,
    const float2* __restrict__ meta, bf16* __restrict__ o)
{
  const int blk = blockIdx.x;
  const int bh = blk >> 4, sp = blk & 15;
  const int b = bh >> 3, h = bh & 7;
  const int tid = threadIdx.x;
  const int g = tid & 15;
  const int j = tid >> 4;               // 0..11
  const int vc = h*DVz + sp*12 + j;

  __shared__ float kq[2][16][192];      // [buf][step][96 k | 96 q]

  const us* KQ = kqn + (size_t)b*Tz*1536 + h*192 + tid;
  const us* VP = (const us*)vn + (size_t)b*Tz*VDz + vc;
  us* op = (us*)o + (size_t)b*Tz*VDz + vc;
  const float2* MP = meta + (size_t)b*Tz*Hz + h;

  float S[6];
  #pragma unroll
  for (int m=0;m<6;m++) S[m]=0.f;

  float ced[16], egb[16], cvb[16];   // eg, eg*beta, v*beta

  // ---- prologue: stage phase 0 ----
  #pragma unroll
  for (int s=0;s<16;s++){
    kq[0][s][tid] = us2f(KQ[(size_t)s*1536]);
    const float cv = us2f(VP[(size_t)s*VDz]);
    const float2 m = MP[(size_t)s*Hz];
    ced[s] = m.x; egb[s] = m.x*m.y; cvb[s] = cv*m.y;
  }
  __syncthreads();

  for (int ph=0; ph<Tz/16; ph++){
    const int base = ph*16;
    const int p = ph & 1;
    const bool more = (base + 16 < Tz);
    const int nb = more ? base + 16 : base;   // clamp; values unused when !more
    // (1) prefetch next-phase inputs (independent -> issue at top)
    float nkq[16], nv[16]; float2 nm[16];
    #pragma unroll
    for (int s=0;s<16;s++){
      nkq[s] = us2f(KQ[(size_t)(nb+s)*1536]);
      nv[s]  = us2f(VP[(size_t)(nb+s)*VDz]);
      nm[s]  = MP[(size_t)(nb+s)*Hz];
    }
    // (2) consume 16 steps; parity register sets, b64 reads (g*24B: all-banks-once)
    float2 kf[2][3], qf[2][3];
    #pragma unroll
    for (int m=0;m<3;m++){
      kf[0][m] = *(const float2*)&kq[p][0][g*6 + m*2];
      qf[0][m] = *(const float2*)&kq[p][0][96 + g*6 + m*2];
    }
    #pragma unroll
    for (int s=0;s<16;s++){
      const int cu = s & 1, nx = cu ^ 1;
      if (s < 15){
        #pragma unroll
        for (int m=0;m<3;m++){
          kf[nx][m] = *(const float2*)&kq[p][s+1][g*6 + m*2];
          qf[nx][m] = *(const float2*)&kq[p][s+1][96 + g*6 + m*2];
        }
      }
      float a0, a1;
      a0 = kf[cu][0].x*S[0];          a1 = kf[cu][0].y*S[1];
      a0 = fmaf(kf[cu][1].x,S[2],a0); a1 = fmaf(kf[cu][1].y,S[3],a1);
      a0 = fmaf(kf[cu][2].x,S[4],a0); a1 = fmaf(kf[cu][2].y,S[5],a1);
      const float pv = gsum16(a0+a1);
      const float eg = ced[s];
      const float delta = fmaf(-egb[s], pv, cvb[s]);   // (cv - eg*pv)*beta
      float o0, o1, t0;
      t0 = fmaf(eg,S[0], kf[cu][0].x*delta); S[0]=t0; o0 = qf[cu][0].x*t0;
      t0 = fmaf(eg,S[1], kf[cu][0].y*delta); S[1]=t0; o1 = qf[cu][0].y*t0;
      t0 = fmaf(eg,S[2], kf[cu][1].x*delta); S[2]=t0; o0 = fmaf(qf[cu][1].x,t0,o0);
      t0 = fmaf(eg,S[3], kf[cu][1].y*delta); S[3]=t0; o1 = fmaf(qf[cu][1].y,t0,o1);
      t0 = fmaf(eg,S[4], kf[cu][2].x*delta); S[4]=t0; o0 = fmaf(qf[cu][2].x,t0,o0);
      t0 = fmaf(eg,S[5], kf[cu][2].y*delta); S[5]=t0; o1 = fmaf(qf[cu][2].y,t0,o1);
      const float po = gsum16(o0+o1);
      if (g == 0) op[(size_t)(base+s)*VDz] = f2bs(po);
    }
    // (3) stage next phase from prefetched registers (1:1, branch-free)
    if (more){
      #pragma unroll
      for (int s=0;s<16;s++){
        kq[p^1][s][tid] = nkq[s];
        ced[s] = nm[s].x; egb[s] = nm[s].x*nm[s].y; cvb[s] = nv[s]*nm[s].y;
      }
    }
    __syncthreads();
  }
}

// ---------------- output gate: rmsnorm_dv(o) * silu(gout) ----------------
// 256 threads = 4 waves; wave w handles row blockIdx.x*4 + w.
__global__ __launch_bounds__(256) void gate_out_kernel(
    const bf16* __restrict__ o, const bf16* __restrict__ gout,
    const float* __restrict__ onw, bf16* __restrict__ og)
{
  const int row = blockIdx.x*4 + (threadIdx.x >> 6);
  const size_t base = (size_t)row * DVz;
  const int lane = threadIdx.x & 63;
  const us* O = (const us*)o;
  float x0 = us2f(O[base+lane]), x1 = us2f(O[base+64+lane]), x2 = us2f(O[base+128+lane]);
  float ss = x0*x0 + x1*x1 + x2*x2;
  #pragma unroll
  for (int off=32; off>=1; off>>=1) ss += __shfl_xor(ss, off);
  const float inv = rsqrtf(ss*(1.f/DVz) + 1e-6f);
  const us* G = (const us*)gout;
  us* OG = (us*)og;
  float xs[3] = {x0, x1, x2};
  #pragma unroll
  for (int i=0;i<3;i++){
    const int c = lane + 64*i;
    const float gv = us2f(G[base+c]);
    OG[base+c] = f2bs(xs[i]*inv*onw[c] * siluf_(gv));
  }
}

extern "C" void kernel_launch(void* const* d_in, const int* in_sizes, int n_in,
                              void* d_out, int out_size, void* d_ws, size_t ws_size,
                              hipStream_t stream) {
  const float* x        = (const float*)d_in[0];
  const float* Wq       = (const float*)d_in[1];
  const float* Wk       = (const float*)d_in[2];
  const float* Wv       = (const float*)d_in[3];
  const float* Wb       = (const float*)d_in[4];
  const float* Wa       = (const float*)d_in[5];
  const float* A_log    = (const float*)d_in[6];
  const float* dt_bias  = (const float*)d_in[7];
  const float* conv_q_w = (const float*)d_in[8];
  const float* conv_k_w = (const float*)d_in[9];
  const float* conv_v_w = (const float*)d_in[10];
  const float* Wg       = (const float*)d_in[11];
  const float* onorm_w  = (const float*)d_in[12];
  const float* Wo       = (const float*)d_in[13];
  const float* norm1_w  = (const float*)d_in[14];
  const float* norm2_w  = (const float*)d_in[15];
  const float* Wgate    = (const float*)d_in[16];
  const float* Wup      = (const float*)d_in[17];
  const float* Wdown    = (const float*)d_in[18];

  char* W = (char*)d_ws;
  // bf16-transposed weights (rewritten every launch; deterministic)
  us* WoT    = (us*)(W + 0);           // live thru Wo GEMM
  us* WgateT = (us*)(W + 3145728);     // live thru MLP
  us* WupT   = (us*)(W + 11534336);
  us* WdownT = (us*)(W + 19922944);    // ends 28,311,552
  // concatenated qkvg^T [4608,1024] bf16 (q rows 0-767, k 768-1535, v 1536-3071,
  // g 3072-4607); dead after proj GEMM
  us* WqkvgT = (us*)(W + 28311552);    // ends 37,748,736
  // activations
  bf16*   h_   = (bf16*)  (W + 37748736);   // [8192,1024]; dead after proj GEMM
  bf16*   preq = (bf16*)  (W + 54525952);   // [8192,768];  dead after conv_kq
  bf16*   prek = (bf16*)  (W + 67108864);   // [8192,768];  dead after conv_kq
  bf16*   prev = (bf16*)  (W + 79691776);   // [8192,1536]; dead after conv_apply_v
  float2* meta = (float2*)(W + 104857600);  // [8192,8] float2; dead after scan
  bf16*   gout = (bf16*)  (W + 105906176);  // [8192,1536]; ends 131,072,000 (PEAK)
  // aliases over dead regions
  us*    kqn   = (us*)   (W + 28311552);   // [8192,1536] bf16 over WqkvgT+h_-head (dead after scan)
  bf16*  vn    = (bf16*) (W + 54525952);   // [8192,1536] over preq+prek (dead after scan)
  bf16*  o_    = (bf16*) (W + 79691776);   // [8192,1536] over prev (dead after gate_out)
  float* x2    = (float*)(W + 79691776);   // [8192,1024] f32 over o_+meta+gout-head (post gate_out)
  bf16*  og    = (bf16*) (W + 28311552);   // [8192,1536] over kqn (dead after Wo GEMM)
  bf16*  h2    = (bf16*) (W + 113246208);  // [8192,1024] over gout tail (dead after gate_out)
  bf16*  gateC = (bf16*) (W + 28311552);   // [4096,4096] over og+vn region (dead after Wo GEMM)

  // 0. weight prep (transpose + f32->bf16), single merged launch (18432 tiles)
  wprep_all_kernel<<<18432, 256, 0, stream>>>(
      Wo, Wgate, Wup, Wdown, Wq, Wk, Wv, Wg,
      WoT, WgateT, WupT, WdownT,
      WqkvgT, WqkvgT + 768*1024, WqkvgT + 1536*1024, WqkvgT + 3072*1024);
  // 1. pre-norm
  rmsnorm_kernel<<<BTz, 256, 0, stream>>>(x, norm1_w, h_);
  // 2. merged q/k/v/g projection (one GEMM, scatter epilogue) + meta
  proj_gemm_kernel<<<dim3(36,64), 256, 0, stream>>>(h_, WqkvgT,
      (us*)preq, (us*)prek, (us*)prev, (us*)gout, BTz, 4608, Dz);
  beta_g_kernel<<<BTz, 256, 0, stream>>>(h_, Wb, Wa, A_log, dt_bias, meta);
  // 3. fused conv+silu+l2+scale -> kqn; conv+silu -> vn; consume-only scan
  conv_kq_kernel<<<BTz*Hz/4, 256, 0, stream>>>(preq, prek, conv_q_w, conv_k_w, kqn);
  conv_apply_v_kernel<<<dim3(6, BTz), 256, 0, stream>>>(prev, conv_v_w, vn);
  scan_kernel<<<Bz*Hz*16, 192, 0, stream>>>(kqn, vn, meta, o_);
  // 4. output gating + Wo projection with residual
  gate_out_kernel<<<BTz*Hz/4, 256, 0, stream>>>(o_, gout, onorm_w, og);
  mgemm_kernel<1><<<dim3(8,64), 256, 0, stream>>>(og, WoT, x, x2, BTz, Dz, VDz);
  // 5. MLP, chunked over 2 x 4096 rows; gate&up fused into one dual GEMM
  rmsnorm_kernel<<<BTz, 256, 0, stream>>>(x2, norm2_w, h2);
  for (int c = 0; c < 2; c++){
    const bf16*  h2c = h2 + (size_t)c*4096*Dz;
    const float* x2c = x2 + (size_t)c*4096*Dz;
    float*       out = (float*)d_out + (size_t)c*4096*Dz;
    mgemm_dual_kernel<<<dim3(32,32), 256, 0, stream>>>(h2c, WgateT, WupT, (us*)gateC,
                                                       4096, Iz, Dz);
    mgemm_kernel<1><<<dim3(8,32),  256, 0, stream>>>(gateC, WdownT, x2c, out, 4096, Dz, Iz);
  }
}

// Round 23
// 1132.283 us; speedup vs baseline: 1.0178x; 1.0001x over previous
//
#include <hip/hip_runtime.h>
#include <hip/hip_bf16.h>

typedef __hip_bfloat16 bf16;
typedef unsigned short us;
typedef short short8v __attribute__((ext_vector_type(8)));
typedef float f32x4 __attribute__((ext_vector_type(4)));
typedef __attribute__((address_space(3))) unsigned int lds_u32;
typedef __attribute__((address_space(1))) const unsigned int glb_u32;

#define GLOAD16(gp, lp) __builtin_amdgcn_global_load_lds((glb_u32*)(gp), (lds_u32*)(lp), 16, 0, 0)

#define Bz 4
#define Tz 2048
#define Dz 1024
#define Hz 8
#define DKz 96
#define DVz 192
#define KDz 768
#define VDz 1536
#define Iz 4096
#define BTz (Bz*Tz)

static __device__ __forceinline__ float us2f(us s){
  return __uint_as_float(((unsigned)s) << 16);
}
static __device__ __forceinline__ us f2bs(float f){
  bf16 t = __float2bfloat16(f);
  return *(us*)&t;
}
static __device__ __forceinline__ float sigmoidf_(float x){ return 1.f/(1.f+expf(-x)); }
static __device__ __forceinline__ float siluf_(float x){ return x*sigmoidf_(x); }

// DPP lane-group sums (VALU pipe, no DS):
#define DPPADD(x, ctrl) \
  ((x) + __int_as_float(__builtin_amdgcn_update_dpp(0, __float_as_int(x), (ctrl), 0xF, 0xF, true)))
static __device__ __forceinline__ float gsum16(float x){
  x = DPPADD(x, 0xB1);   // quad_perm [1,0,3,2] : + lane^1
  x = DPPADD(x, 0x4E);   // quad_perm [2,3,0,1] : + lane^2
  x = DPPADD(x, 0x141);  // row_half_mirror     : + other quad (8-group sum)
  x = DPPADD(x, 0x140);  // row_mirror          : + other 8-half (16-group sum)
  return x;
}

// ---------------- merged weight prep: 8 segments of W[K,N] f32 -> WT[N,K] bf16 -------
// Segment tiles (K/32 * N/32): Wo 1536, Wgate 4096, Wup 4096, Wdown 4096,
// Wq 768, Wk 768, Wv 1536, Wg 1536  => 18432 blocks total.
__global__ __launch_bounds__(256) void wprep_all_kernel(
    const float* __restrict__ s0, const float* __restrict__ s1,
    const float* __restrict__ s2, const float* __restrict__ s3,
    const float* __restrict__ s4, const float* __restrict__ s5,
    const float* __restrict__ s6, const float* __restrict__ s7,
    us* __restrict__ d0, us* __restrict__ d1, us* __restrict__ d2,
    us* __restrict__ d3, us* __restrict__ d4, us* __restrict__ d5,
    us* __restrict__ d6, us* __restrict__ d7)
{
  const int NT[8] = {1536,4096,4096,4096,768,768,1536,1536};
  const int KS[8] = {1536,1024,1024,4096,1024,1024,1024,1024};
  const int NS[8] = {1024,4096,4096,1024,768,768,1536,1536};
  int b = blockIdx.x, seg = 0;
  #pragma unroll
  for (int i=0;i<7;i++){ if (b >= NT[seg]){ b -= NT[seg]; seg++; } }
  const float* src = seg==0?s0: seg==1?s1: seg==2?s2: seg==3?s3:
                     seg==4?s4: seg==5?s5: seg==6?s6: s7;
  us* dst = seg==0?d0: seg==1?d1: seg==2?d2: seg==3?d3:
            seg==4?d4: seg==5?d5: seg==6?d6: d7;
  const int K = KS[seg], N = NS[seg];
  const int ktiles = K >> 5;
  const int k0 = (b % ktiles)*32, n0 = (b / ktiles)*32;

  __shared__ float t[32][33];
  const int c = threadIdx.x & 31, r8 = threadIdx.x >> 5;
  #pragma unroll
  for (int i=0;i<4;i++){
    const int r = r8 + i*8;
    t[r][c] = src[(size_t)(k0+r)*N + n0 + c];
  }
  __syncthreads();
  #pragma unroll
  for (int i=0;i<4;i++){
    const int r = r8 + i*8;
    dst[(size_t)(n0+r)*K + k0 + c] = f2bs(t[c][r]);
  }
}

// ---------------- RMSNorm (f32 in -> bf16 out, f32 weights) ----------------
__global__ __launch_bounds__(256) void rmsnorm_kernel(
    const float* __restrict__ x, const float* __restrict__ w, bf16* __restrict__ out)
{
  const int row = blockIdx.x;
  const float* xr = x + (size_t)row*Dz;
  const int i0 = threadIdx.x*4;
  float4 xv = *(const float4*)(xr + i0);
  float ss = xv.x*xv.x+xv.y*xv.y+xv.z*xv.z+xv.w*xv.w;
  #pragma unroll
  for (int off=32; off>=1; off>>=1) ss += __shfl_xor(ss, off);
  __shared__ float red[4];
  if ((threadIdx.x&63)==0) red[threadIdx.x>>6] = ss;
  __syncthreads();
  ss = red[0]+red[1]+red[2]+red[3];
  const float inv = rsqrtf(ss*(1.f/Dz) + 1e-6f);
  float4 wv = *(const float4*)(w + i0);
  ushort4 ov;
  ov.x=f2bs(xv.x*inv*wv.x); ov.y=f2bs(xv.y*inv*wv.y);
  ov.z=f2bs(xv.z*inv*wv.z); ov.w=f2bs(xv.w*inv*wv.w);
  *(ushort4*)((us*)out + (size_t)row*Dz + i0) = ov;
}

// ------------- MFMA GEMM: C[M,N] = A[M,K](bf16) @ BT[N,K](bf16)^T (+res) -------------
// XCD-aware swizzle: grids must have (gridX*gridY)%8==0 (all call sites satisfy).
// MODE 0: write bf16.  MODE 1: write f32 + f32 residual.
template<int MODE>
__global__ __launch_bounds__(256, 2) void mgemm_kernel(
    const bf16* __restrict__ A, const us* __restrict__ BT,
    const void* __restrict__ res, void* __restrict__ Cout,
    int M, int N, int K)
{
  __shared__ us As[128*64];
  __shared__ us Bs[128*64];
  const int nwgx = gridDim.x;
  const int lid = blockIdx.y*nwgx + blockIdx.x;
  const int cpx = (nwgx*gridDim.y) >> 3;
  const int swz = (lid & 7)*cpx + (lid >> 3);
  const int m0 = (swz / nwgx)*128, n0 = (swz % nwgx)*128;
  const int tid = threadIdx.x;
  const int wid = tid >> 6, lane = tid & 63;
  const int wr = wid >> 1, wc = wid & 1;
  const int fq = lane >> 4, fr = lane & 15;

  const us* Ab = (const us*)A + (size_t)(m0 + (tid>>3))*K + (tid&7)*8;
  const us* Bb = BT + (size_t)(n0 + (tid>>3))*K + (tid&7)*8;
  char* AsB = (char*)As;
  char* BsB = (char*)Bs;
  const int ldsoff = wid*1024;

  f32x4 acc[4][4] = {};
  const int nk = K >> 6;
  for (int kt = 0; kt < nk; ++kt){
    const int kb = kt*64;
    #pragma unroll
    for (int i=0;i<4;i++){
      GLOAD16(Ab + (size_t)(32*i)*K + kb, AsB + ldsoff + i*4096);
      GLOAD16(Bb + (size_t)(32*i)*K + kb, BsB + ldsoff + i*4096);
    }
    __syncthreads();
    #pragma unroll
    for (int ks=0; ks<2; ks++){
      short8v af[4], bf[4];
      #pragma unroll
      for (int r=0;r<4;r++)
        af[r] = *(const short8v*)&As[(wr*64 + r*16 + fr)*64 + ks*32 + fq*8];
      #pragma unroll
      for (int c=0;c<4;c++)
        bf[c] = *(const short8v*)&Bs[(wc*64 + c*16 + fr)*64 + ks*32 + fq*8];
      #pragma unroll
      for (int r=0;r<4;r++)
        #pragma unroll
        for (int c=0;c<4;c++)
          acc[r][c] = __builtin_amdgcn_mfma_f32_16x16x32_bf16(af[r], bf[c], acc[r][c], 0, 0, 0);
    }
    __syncthreads();
  }
  #pragma unroll
  for (int r=0;r<4;r++){
    #pragma unroll
    for (int c=0;c<4;c++){
      const int col = n0 + wc*64 + c*16 + fr;
      #pragma unroll
      for (int jj=0;jj<4;jj++){
        const int row = m0 + wr*64 + r*16 + fq*4 + jj;
        const size_t idx = (size_t)row*N + col;
        const float a = acc[r][c][jj];
        if (MODE==0){
          ((us*)Cout)[idx] = f2bs(a);
        } else {
          ((float*)Cout)[idx] = a + ((const float*)res)[idx];
        }
      }
    }
  }
}

// ------- merged QKVG projection GEMM: A[M,1024] @ qkvgT[4608,1024]^T -------
__global__ __launch_bounds__(256, 2) void proj_gemm_kernel(
    const bf16* __restrict__ A, const us* __restrict__ BT,
    us* __restrict__ preq, us* __restrict__ prek,
    us* __restrict__ prev, us* __restrict__ gout,
    int M, int N, int K)
{
  __shared__ us As[128*64];
  __shared__ us Bs[128*64];
  const int nwgx = gridDim.x;
  const int lid = blockIdx.y*nwgx + blockIdx.x;
  const int cpx = (nwgx*gridDim.y) >> 3;
  const int swz = (lid & 7)*cpx + (lid >> 3);
  const int m0 = (swz / nwgx)*128, n0 = (swz % nwgx)*128;
  const int tid = threadIdx.x;
  const int wid = tid >> 6, lane = tid & 63;
  const int wr = wid >> 1, wc = wid & 1;
  const int fq = lane >> 4, fr = lane & 15;

  const us* Ab = (const us*)A + (size_t)(m0 + (tid>>3))*K + (tid&7)*8;
  const us* Bb = BT + (size_t)(n0 + (tid>>3))*K + (tid&7)*8;
  char* AsB = (char*)As;
  char* BsB = (char*)Bs;
  const int ldsoff = wid*1024;

  f32x4 acc[4][4] = {};
  const int nk = K >> 6;
  for (int kt = 0; kt < nk; ++kt){
    const int kb = kt*64;
    #pragma unroll
    for (int i=0;i<4;i++){
      GLOAD16(Ab + (size_t)(32*i)*K + kb, AsB + ldsoff + i*4096);
      GLOAD16(Bb + (size_t)(32*i)*K + kb, BsB + ldsoff + i*4096);
    }
    __syncthreads();
    #pragma unroll
    for (int ks=0; ks<2; ks++){
      short8v af[4], bf[4];
      #pragma unroll
      for (int r=0;r<4;r++)
        af[r] = *(const short8v*)&As[(wr*64 + r*16 + fr)*64 + ks*32 + fq*8];
      #pragma unroll
      for (int c=0;c<4;c++)
        bf[c] = *(const short8v*)&Bs[(wc*64 + c*16 + fr)*64 + ks*32 + fq*8];
      #pragma unroll
      for (int r=0;r<4;r++)
        #pragma unroll
        for (int c=0;c<4;c++)
          acc[r][c] = __builtin_amdgcn_mfma_f32_16x16x32_bf16(af[r], bf[c], acc[r][c], 0, 0, 0);
    }
    __syncthreads();
  }
  // block-uniform scatter target (col tiles align to 768/1536/3072 boundaries)
  us* dst; int col0, Nout;
  if (n0 < 768)      { dst = preq; col0 = n0;        Nout = 768;  }
  else if (n0 < 1536){ dst = prek; col0 = n0 - 768;  Nout = 768;  }
  else if (n0 < 3072){ dst = prev; col0 = n0 - 1536; Nout = 1536; }
  else               { dst = gout; col0 = n0 - 3072; Nout = 1536; }
  #pragma unroll
  for (int r=0;r<4;r++){
    #pragma unroll
    for (int c=0;c<4;c++){
      const int col = col0 + wc*64 + c*16 + fr;
      #pragma unroll
      for (int jj=0;jj<4;jj++){
        const int row = m0 + wr*64 + r*16 + fq*4 + jj;
        dst[(size_t)row*Nout + col] = f2bs(acc[r][c][jj]);
      }
    }
  }
}

// ------- fused dual GEMM: out = silu(A@Wg^T) * (A@Wu^T), bf16 -------
__global__ __launch_bounds__(256, 2) void mgemm_dual_kernel(
    const bf16* __restrict__ A, const us* __restrict__ BT1, const us* __restrict__ BT2,
    us* __restrict__ Cout, int M, int N, int K)
{
  __shared__ us As[128*64];
  __shared__ us Bs1[128*64];
  __shared__ us Bs2[128*64];
  const int nwgx = gridDim.x;
  const int lid = blockIdx.y*nwgx + blockIdx.x;
  const int cpx = (nwgx*gridDim.y) >> 3;
  const int swz = (lid & 7)*cpx + (lid >> 3);
  const int m0 = (swz / nwgx)*128, n0 = (swz % nwgx)*128;
  const int tid = threadIdx.x;
  const int wid = tid >> 6, lane = tid & 63;
  const int wr = wid >> 1, wc = wid & 1;
  const int fq = lane >> 4, fr = lane & 15;

  const us* Ab  = (const us*)A + (size_t)(m0 + (tid>>3))*K + (tid&7)*8;
  const us* Bb1 = BT1 + (size_t)(n0 + (tid>>3))*K + (tid&7)*8;
  const us* Bb2 = BT2 + (size_t)(n0 + (tid>>3))*K + (tid&7)*8;
  char* AsB  = (char*)As;
  char* BsB1 = (char*)Bs1;
  char* BsB2 = (char*)Bs2;
  const int ldsoff = wid*1024;

  f32x4 acc1[4][4] = {};
  f32x4 acc2[4][4] = {};
  const int nk = K >> 6;
  for (int kt = 0; kt < nk; ++kt){
    const int kb = kt*64;
    #pragma unroll
    for (int i=0;i<4;i++){
      GLOAD16(Ab  + (size_t)(32*i)*K + kb, AsB  + ldsoff + i*4096);
      GLOAD16(Bb1 + (size_t)(32*i)*K + kb, BsB1 + ldsoff + i*4096);
      GLOAD16(Bb2 + (size_t)(32*i)*K + kb, BsB2 + ldsoff + i*4096);
    }
    __syncthreads();
    #pragma unroll
    for (int ks=0; ks<2; ks++){
      short8v af[4], bf1[4], bf2[4];
      #pragma unroll
      for (int r=0;r<4;r++)
        af[r] = *(const short8v*)&As[(wr*64 + r*16 + fr)*64 + ks*32 + fq*8];
      #pragma unroll
      for (int c=0;c<4;c++){
        bf1[c] = *(const short8v*)&Bs1[(wc*64 + c*16 + fr)*64 + ks*32 + fq*8];
        bf2[c] = *(const short8v*)&Bs2[(wc*64 + c*16 + fr)*64 + ks*32 + fq*8];
      }
      #pragma unroll
      for (int r=0;r<4;r++)
        #pragma unroll
        for (int c=0;c<4;c++){
          acc1[r][c] = __builtin_amdgcn_mfma_f32_16x16x32_bf16(af[r], bf1[c], acc1[r][c], 0, 0, 0);
          acc2[r][c] = __builtin_amdgcn_mfma_f32_16x16x32_bf16(af[r], bf2[c], acc2[r][c], 0, 0, 0);
        }
    }
    __syncthreads();
  }
  #pragma unroll
  for (int r=0;r<4;r++){
    #pragma unroll
    for (int c=0;c<4;c++){
      const int col = n0 + wc*64 + c*16 + fr;
      #pragma unroll
      for (int jj=0;jj<4;jj++){
        const int row = m0 + wr*64 + r*16 + fq*4 + jj;
        Cout[(size_t)row*N + col] = f2bs(siluf_(acc1[r][c][jj]) * acc2[r][c][jj]);
      }
    }
  }
}

// ------- beta / exp(g) projections -> meta = (exp(g), beta) float2 -------
__global__ __launch_bounds__(256) void beta_g_kernel(
    const bf16* __restrict__ hh, const float* __restrict__ Wb, const float* __restrict__ Wa,
    const float* __restrict__ A_log, const float* __restrict__ dt_bias,
    float2* __restrict__ meta)
{
  const int row = blockIdx.x;
  const us* hr = (const us*)hh + (size_t)row*Dz;
  float ab[8]={0,0,0,0,0,0,0,0}, aa[8]={0,0,0,0,0,0,0,0};
  for (int kk=threadIdx.x; kk<Dz; kk+=256){
    const float hv = us2f(hr[kk]);
    float4 b0 = *(const float4*)(Wb + kk*8);
    float4 b1 = *(const float4*)(Wb + kk*8 + 4);
    float4 a0 = *(const float4*)(Wa + kk*8);
    float4 a1 = *(const float4*)(Wa + kk*8 + 4);
    ab[0]=fmaf(hv,b0.x,ab[0]); ab[1]=fmaf(hv,b0.y,ab[1]);
    ab[2]=fmaf(hv,b0.z,ab[2]); ab[3]=fmaf(hv,b0.w,ab[3]);
    ab[4]=fmaf(hv,b1.x,ab[4]); ab[5]=fmaf(hv,b1.y,ab[5]);
    ab[6]=fmaf(hv,b1.z,ab[6]); ab[7]=fmaf(hv,b1.w,ab[7]);
    aa[0]=fmaf(hv,a0.x,aa[0]); aa[1]=fmaf(hv,a0.y,aa[1]);
    aa[2]=fmaf(hv,a0.z,aa[2]); aa[3]=fmaf(hv,a0.w,aa[3]);
    aa[4]=fmaf(hv,a1.x,aa[4]); aa[5]=fmaf(hv,a1.y,aa[5]);
    aa[6]=fmaf(hv,a1.z,aa[6]); aa[7]=fmaf(hv,a1.w,aa[7]);
  }
  #pragma unroll
  for (int off=32; off>=1; off>>=1){
    #pragma unroll
    for (int n=0;n<8;n++){ ab[n]+=__shfl_xor(ab[n],off); aa[n]+=__shfl_xor(aa[n],off); }
  }
  __shared__ float red[4][16];
  const int wv = threadIdx.x>>6, ln = threadIdx.x&63;
  if (ln==0){
    #pragma unroll
    for (int n=0;n<8;n++){ red[wv][n]=ab[n]; red[wv][8+n]=aa[n]; }
  }
  __syncthreads();
  if (threadIdx.x < 8){
    const int n = threadIdx.x;
    float sb = red[0][n]+red[1][n]+red[2][n]+red[3][n];
    float sa = red[0][8+n]+red[1][8+n]+red[2][8+n]+red[3][8+n];
    float xx = sa + dt_bias[n];
    float sp = (xx > 20.f) ? xx : log1pf(expf(xx));
    float eg = expf(-expf(A_log[n])*sp);
    float bt = 1.f/(1.f+expf(-sb));
    meta[(size_t)row*Hz + n] = make_float2(eg, bt);
  }
}

// ------- fused conv(K=4)+SiLU+l2norm+scale for k,q -> kqn[bt][h][96k|96q] bf16 -------
// 256 threads = 4 waves; wave w handles unit (bt,h) = blockIdx.x*4 + w.
__global__ __launch_bounds__(256) void conv_kq_kernel(
    const bf16* __restrict__ preq, const bf16* __restrict__ prek,
    const float* __restrict__ wqc, const float* __restrict__ wkc,
    us* __restrict__ kqn)
{
  const int u = blockIdx.x*4 + (threadIdx.x >> 6);
  const int h = u & 7; const int bt = u >> 3;
  const int t = bt & (Tz-1);
  const int lane = threadIdx.x & 63;
  const us* Q = (const us*)preq;
  const us* K = (const us*)prek;
  const int c0 = h*DKz + lane, c1 = c0 + 64;
  const bool hi = lane < 32;
  float yq0=0.f, yq1=0.f, yk0=0.f, yk1=0.f;
  #pragma unroll
  for (int i=0;i<4;i++){
    const int ti = t - 3 + i;
    if (ti >= 0){
      const size_t rowb = (size_t)(bt-3+i)*KDz;
      yq0 = fmaf(us2f(Q[rowb + c0]), wqc[c0*4+i], yq0);
      yk0 = fmaf(us2f(K[rowb + c0]), wkc[c0*4+i], yk0);
      if (hi){
        yq1 = fmaf(us2f(Q[rowb + c1]), wqc[c1*4+i], yq1);
        yk1 = fmaf(us2f(K[rowb + c1]), wkc[c1*4+i], yk1);
      }
    }
  }
  yq0 = siluf_(yq0); yk0 = siluf_(yk0);
  yq1 = hi ? siluf_(yq1) : 0.f;
  yk1 = hi ? siluf_(yk1) : 0.f;
  float ssq = yq0*yq0 + yq1*yq1;
  float ssk = yk0*yk0 + yk1*yk1;
  #pragma unroll
  for (int off=32; off>=1; off>>=1){ ssq += __shfl_xor(ssq,off); ssk += __shfl_xor(ssk,off); }
  const float iq = rsqrtf(ssq + 1e-6f) * 0.10206207262f;  // invq * dk^-0.5
  const float ik = rsqrtf(ssk + 1e-6f);
  const size_t base = (size_t)bt*1536 + (size_t)h*192;
  kqn[base + lane]      = f2bs(yk0*ik);
  kqn[base + 96 + lane] = f2bs(yq0*iq);
  if (hi){
    kqn[base + 64 + lane]      = f2bs(yk1*ik);
    kqn[base + 96 + 64 + lane] = f2bs(yq1*iq);
  }
}

// ------- apply conv+SiLU to v -> vn bf16 -------
__global__ __launch_bounds__(256) void conv_apply_v_kernel(
    const bf16* __restrict__ prev, const float* __restrict__ wvc, bf16* __restrict__ vn)
{
  const int bt = blockIdx.y; const int ccol = blockIdx.x*256 + threadIdx.x;
  const int t = bt & (Tz-1);
  const us* X = (const us*)prev;
  float acc = 0.f;
  #pragma unroll
  for (int i=0;i<4;i++){
    const int ti = t - 3 + i;
    if (ti >= 0) acc = fmaf(us2f(X[(size_t)(bt-3+i)*VDz + ccol]), wvc[ccol*4+i], acc);
  }
  ((us*)vn)[(size_t)bt*VDz + ccol] = f2bs(siluf_(acc));
}

// ---------------- gated delta-rule scan, consume-only, 16-way split ----------------
// Grid = Bz*Hz*16; block (bh, sp) owns v-cols [sp*12, sp*12+12).
// 192 threads: tid = j*16 + g; thread owns S[g*6 .. g*6+5][col sp*12+j].
// 2 blocks/CU -> 6 waves/CU for stall overlap.
// Phase = 16 steps (barriers halved vs 8-step; prefetch wait amortized 2x).
__global__ __launch_bounds__(192, 1) void scan_kernel(
    const us* __restrict__ kqn, const bf16* __restrict__ vn,
    const float2* __restrict__ meta, bf16* __restrict__ o)
{
  const int blk = blockIdx.x;
  const int bh = blk >> 4, sp = blk & 15;
  const int b = bh >> 3, h = bh & 7;
  const int tid = threadIdx.x;
  const int g = tid & 15;
  const int j = tid >> 4;               // 0..11
  const int vc = h*DVz + sp*12 + j;

  __shared__ float kq[2][16][192];      // [buf][step][96 k | 96 q]

  const us* KQ = kqn + (size_t)b*Tz*1536 + h*192 + tid;
  const us* VP = (const us*)vn + (size_t)b*Tz*VDz + vc;
  us* op = (us*)o + (size_t)b*Tz*VDz + vc;
  const float2* MP = meta + (size_t)b*Tz*Hz + h;

  float S[6];
  #pragma unroll
  for (int m=0;m<6;m++) S[m]=0.f;

  float ced[16], egb[16], cvb[16];   // eg, eg*beta, v*beta

  // ---- prologue: stage phase 0 ----
  #pragma unroll
  for (int s=0;s<16;s++){
    kq[0][s][tid] = us2f(KQ[(size_t)s*1536]);
    const float cv = us2f(VP[(size_t)s*VDz]);
    const float2 m = MP[(size_t)s*Hz];
    ced[s] = m.x; egb[s] = m.x*m.y; cvb[s] = cv*m.y;
  }
  __syncthreads();

  for (int ph=0; ph<Tz/16; ph++){
    const int base = ph*16;
    const int p = ph & 1;
    const bool more = (base + 16 < Tz);
    const int nb = more ? base + 16 : base;   // clamp; values unused when !more
    // (1) prefetch next-phase inputs (independent -> issue at top)
    float nkq[16], nv[16]; float2 nm[16];
    #pragma unroll
    for (int s=0;s<16;s++){
      nkq[s] = us2f(KQ[(size_t)(nb+s)*1536]);
      nv[s]  = us2f(VP[(size_t)(nb+s)*VDz]);
      nm[s]  = MP[(size_t)(nb+s)*Hz];
    }
    // (2) consume 16 steps; parity register sets, b64 reads (g*24B: all-banks-once)
    float2 kf[2][3], qf[2][3];
    #pragma unroll
    for (int m=0;m<3;m++){
      kf[0][m] = *(const float2*)&kq[p][0][g*6 + m*2];
      qf[0][m] = *(const float2*)&kq[p][0][96 + g*6 + m*2];
    }
    #pragma unroll
    for (int s=0;s<16;s++){
      const int cu = s & 1, nx = cu ^ 1;
      if (s < 15){
        #pragma unroll
        for (int m=0;m<3;m++){
          kf[nx][m] = *(const float2*)&kq[p][s+1][g*6 + m*2];
          qf[nx][m] = *(const float2*)&kq[p][s+1][96 + g*6 + m*2];
        }
      }
      float a0, a1;
      a0 = kf[cu][0].x*S[0];          a1 = kf[cu][0].y*S[1];
      a0 = fmaf(kf[cu][1].x,S[2],a0); a1 = fmaf(kf[cu][1].y,S[3],a1);
      a0 = fmaf(kf[cu][2].x,S[4],a0); a1 = fmaf(kf[cu][2].y,S[5],a1);
      const float pv = gsum16(a0+a1);
      const float eg = ced[s];
      const float delta = fmaf(-egb[s], pv, cvb[s]);   // (cv - eg*pv)*beta
      float o0, o1, t0;
      t0 = fmaf(eg,S[0], kf[cu][0].x*delta); S[0]=t0; o0 = qf[cu][0].x*t0;
      t0 = fmaf(eg,S[1], kf[cu][0].y*delta); S[1]=t0; o1 = qf[cu][0].y*t0;
      t0 = fmaf(eg,S[2], kf[cu][1].x*delta); S[2]=t0; o0 = fmaf(qf[cu][1].x,t0,o0);
      t0 = fmaf(eg,S[3], kf[cu][1].y*delta); S[3]=t0; o1 = fmaf(qf[cu][1].y,t0,o1);
      t0 = fmaf(eg,S[4], kf[cu][2].x*delta); S[4]=t0; o0 = fmaf(qf[cu][2].x,t0,o0);
      t0 = fmaf(eg,S[5], kf[cu][2].y*delta); S[5]=t0; o1 = fmaf(qf[cu][2].y,t0,o1);
      const float po = gsum16(o0+o1);
      if (g == 0) op[(size_t)(base+s)*VDz] = f2bs(po);
    }
    // (3) stage next phase from prefetched registers (1:1, branch-free)
    if (more){
      #pragma unroll
      for (int s=0;s<16;s++){
        kq[p^1][s][tid] = nkq[s];
        ced[s] = nm[s].x; egb[s] = nm[s].x*nm[s].y; cvb[s] = nv[s]*nm[s].y;
      }
    }
    __syncthreads();
  }
}

// ---------------- output gate: rmsnorm_dv(o) * silu(gout) ----------------
// 256 threads = 4 waves; wave w handles row blockIdx.x*4 + w.
__global__ __launch_bounds__(256) void gate_out_kernel(
    const bf16* __restrict__ o, const bf16* __restrict__ gout,
    const float* __restrict__ onw, bf16* __restrict__ og)
{
  const int row = blockIdx.x*4 + (threadIdx.x >> 6);
  const size_t base = (size_t)row * DVz;
  const int lane = threadIdx.x & 63;
  const us* O = (const us*)o;
  float x0 = us2f(O[base+lane]), x1 = us2f(O[base+64+lane]), x2 = us2f(O[base+128+lane]);
  float ss = x0*x0 + x1*x1 + x2*x2;
  #pragma unroll
  for (int off=32; off>=1; off>>=1) ss += __shfl_xor(ss, off);
  const float inv = rsqrtf(ss*(1.f/DVz) + 1e-6f);
  const us* G = (const us*)gout;
  us* OG = (us*)og;
  float xs[3] = {x0, x1, x2};
  #pragma unroll
  for (int i=0;i<3;i++){
    const int c = lane + 64*i;
    const float gv = us2f(G[base+c]);
    OG[base+c] = f2bs(xs[i]*inv*onw[c] * siluf_(gv));
  }
}

extern "C" void kernel_launch(void* const* d_in, const int* in_sizes, int n_in,
                              void* d_out, int out_size, void* d_ws, size_t ws_size,
                              hipStream_t stream) {
  const float* x        = (const float*)d_in[0];
  const float* Wq       = (const float*)d_in[1];
  const float* Wk       = (const float*)d_in[2];
  const float* Wv       = (const float*)d_in[3];
  const float* Wb       = (const float*)d_in[4];
  const float* Wa       = (const float*)d_in[5];
  const float* A_log    = (const float*)d_in[6];
  const float* dt_bias  = (const float*)d_in[7];
  const float* conv_q_w = (const float*)d_in[8];
  const float* conv_k_w = (const float*)d_in[9];
  const float* conv_v_w = (const float*)d_in[10];
  const float* Wg       = (const float*)d_in[11];
  const float* onorm_w  = (const float*)d_in[12];
  const float* Wo       = (const float*)d_in[13];
  const float* norm1_w  = (const float*)d_in[14];
  const float* norm2_w  = (const float*)d_in[15];
  const float* Wgate    = (const float*)d_in[16];
  const float* Wup      = (const float*)d_in[17];
  const float* Wdown    = (const float*)d_in[18];

  char* W = (char*)d_ws;
  // bf16-transposed weights (rewritten every launch; deterministic)
  us* WoT    = (us*)(W + 0);           // live thru Wo GEMM
  us* WgateT = (us*)(W + 3145728);     // live thru MLP
  us* WupT   = (us*)(W + 11534336);
  us* WdownT = (us*)(W + 19922944);    // ends 28,311,552
  // concatenated qkvg^T [4608,1024] bf16 (q rows 0-767, k 768-1535, v 1536-3071,
  // g 3072-4607); dead after proj GEMM
  us* WqkvgT = (us*)(W + 28311552);    // ends 37,748,736
  // activations
  bf16*   h_   = (bf16*)  (W + 37748736);   // [8192,1024]; dead after proj GEMM
  bf16*   preq = (bf16*)  (W + 54525952);   // [8192,768];  dead after conv_kq
  bf16*   prek = (bf16*)  (W + 67108864);   // [8192,768];  dead after conv_kq
  bf16*   prev = (bf16*)  (W + 79691776);   // [8192,1536]; dead after conv_apply_v
  float2* meta = (float2*)(W + 104857600);  // [8192,8] float2; dead after scan
  bf16*   gout = (bf16*)  (W + 105906176);  // [8192,1536]; ends 131,072,000 (PEAK)
  // aliases over dead regions
  us*    kqn   = (us*)   (W + 28311552);   // [8192,1536] bf16 over WqkvgT+h_-head (dead after scan)
  bf16*  vn    = (bf16*) (W + 54525952);   // [8192,1536] over preq+prek (dead after scan)
  bf16*  o_    = (bf16*) (W + 79691776);   // [8192,1536] over prev (dead after gate_out)
  float* x2    = (float*)(W + 79691776);   // [8192,1024] f32 over o_+meta+gout-head (post gate_out)
  bf16*  og    = (bf16*) (W + 28311552);   // [8192,1536] over kqn (dead after Wo GEMM)
  bf16*  h2    = (bf16*) (W + 113246208);  // [8192,1024] over gout tail (dead after gate_out)
  bf16*  gateC = (bf16*) (W + 28311552);   // [4096,4096] over og+vn region (dead after Wo GEMM)

  // 0. weight prep (transpose + f32->bf16), single merged launch (18432 tiles)
  wprep_all_kernel<<<18432, 256, 0, stream>>>(
      Wo, Wgate, Wup, Wdown, Wq, Wk, Wv, Wg,
      WoT, WgateT, WupT, WdownT,
      WqkvgT, WqkvgT + 768*1024, WqkvgT + 1536*1024, WqkvgT + 3072*1024);
  // 1. pre-norm
  rmsnorm_kernel<<<BTz, 256, 0, stream>>>(x, norm1_w, h_);
  // 2. merged q/k/v/g projection (one GEMM, scatter epilogue) + meta
  proj_gemm_kernel<<<dim3(36,64), 256, 0, stream>>>(h_, WqkvgT,
      (us*)preq, (us*)prek, (us*)prev, (us*)gout, BTz, 4608, Dz);
  beta_g_kernel<<<BTz, 256, 0, stream>>>(h_, Wb, Wa, A_log, dt_bias, meta);
  // 3. fused conv+silu+l2+scale -> kqn; conv+silu -> vn; consume-only scan
  conv_kq_kernel<<<BTz*Hz/4, 256, 0, stream>>>(preq, prek, conv_q_w, conv_k_w, kqn);
  conv_apply_v_kernel<<<dim3(6, BTz), 256, 0, stream>>>(prev, conv_v_w, vn);
  scan_kernel<<<Bz*Hz*16, 192, 0, stream>>>(kqn, vn, meta, o_);
  // 4. output gating + Wo projection with residual
  gate_out_kernel<<<BTz*Hz/4, 256, 0, stream>>>(o_, gout, onorm_w, og);
  mgemm_kernel<1><<<dim3(8,64), 256, 0, stream>>>(og, WoT, x, x2, BTz, Dz, VDz);
  // 5. MLP, chunked over 2 x 4096 rows; gate&up fused into one dual GEMM
  rmsnorm_kernel<<<BTz, 256, 0, stream>>>(x2, norm2_w, h2);
  for (int c = 0; c < 2; c++){
    const bf16*  h2c = h2 + (size_t)c*4096*Dz;
    const float* x2c = x2 + (size_t)c*4096*Dz;
    float*       out = (float*)d_out + (size_t)c*4096*Dz;
    mgemm_dual_kernel<<<dim3(32,32), 256, 0, stream>>>(h2c, WgateT, WupT, (us*)gateC,
                                                       4096, Iz, Dz);
    mgemm_kernel<1><<<dim3(8,32),  256, 0, stream>>>(gateC, WdownT, x2c, out, 4096, Dz, Iz);
  }
}

// Round 24
// 1131.172 us; speedup vs baseline: 1.0188x; 1.0010x over previous
//
#include <hip/hip_runtime.h>
#include <hip/hip_bf16.h>

typedef __hip_bfloat16 bf16;
typedef unsigned short us;
typedef short short8v __attribute__((ext_vector_type(8)));
typedef float f32x4 __attribute__((ext_vector_type(4)));
typedef __attribute__((address_space(3))) unsigned int lds_u32;
typedef __attribute__((address_space(1))) const unsigned int glb_u32;

#define GLOAD16(gp, lp) __builtin_amdgcn_global_load_lds((glb_u32*)(gp), (lds_u32*)(lp), 16, 0, 0)

#define Bz 4
#define Tz 2048
#define Dz 1024
#define Hz 8
#define DKz 96
#define DVz 192
#define KDz 768
#define VDz 1536
#define Iz 4096
#define BTz (Bz*Tz)

static __device__ __forceinline__ float us2f(us s){
  return __uint_as_float(((unsigned)s) << 16);
}
static __device__ __forceinline__ us f2bs(float f){
  bf16 t = __float2bfloat16(f);
  return *(us*)&t;
}
static __device__ __forceinline__ float sigmoidf_(float x){ return 1.f/(1.f+expf(-x)); }
static __device__ __forceinline__ float siluf_(float x){ return x*sigmoidf_(x); }

// DPP lane-group sums (VALU pipe, no DS):
#define DPPADD(x, ctrl) \
  ((x) + __int_as_float(__builtin_amdgcn_update_dpp(0, __float_as_int(x), (ctrl), 0xF, 0xF, true)))
static __device__ __forceinline__ float gsum16(float x){
  x = DPPADD(x, 0xB1);   // quad_perm [1,0,3,2] : + lane^1
  x = DPPADD(x, 0x4E);   // quad_perm [2,3,0,1] : + lane^2
  x = DPPADD(x, 0x141);  // row_half_mirror     : + other quad (8-group sum)
  x = DPPADD(x, 0x140);  // row_mirror          : + other 8-half (16-group sum)
  return x;
}

// ---------------- merged weight prep: 8 segments of W[K,N] f32 -> WT[N,K] bf16 -------
// Segment tiles (K/32 * N/32): Wo 1536, Wgate 4096, Wup 4096, Wdown 4096,
// Wq 768, Wk 768, Wv 1536, Wg 1536  => 18432 blocks total.
__global__ __launch_bounds__(256) void wprep_all_kernel(
    const float* __restrict__ s0, const float* __restrict__ s1,
    const float* __restrict__ s2, const float* __restrict__ s3,
    const float* __restrict__ s4, const float* __restrict__ s5,
    const float* __restrict__ s6, const float* __restrict__ s7,
    us* __restrict__ d0, us* __restrict__ d1, us* __restrict__ d2,
    us* __restrict__ d3, us* __restrict__ d4, us* __restrict__ d5,
    us* __restrict__ d6, us* __restrict__ d7)
{
  const int NT[8] = {1536,4096,4096,4096,768,768,1536,1536};
  const int KS[8] = {1536,1024,1024,4096,1024,1024,1024,1024};
  const int NS[8] = {1024,4096,4096,1024,768,768,1536,1536};
  int b = blockIdx.x, seg = 0;
  #pragma unroll
  for (int i=0;i<7;i++){ if (b >= NT[seg]){ b -= NT[seg]; seg++; } }
  const float* src = seg==0?s0: seg==1?s1: seg==2?s2: seg==3?s3:
                     seg==4?s4: seg==5?s5: seg==6?s6: s7;
  us* dst = seg==0?d0: seg==1?d1: seg==2?d2: seg==3?d3:
            seg==4?d4: seg==5?d5: seg==6?d6: d7;
  const int K = KS[seg], N = NS[seg];
  const int ktiles = K >> 5;
  const int k0 = (b % ktiles)*32, n0 = (b / ktiles)*32;

  __shared__ float t[32][33];
  const int c = threadIdx.x & 31, r8 = threadIdx.x >> 5;
  #pragma unroll
  for (int i=0;i<4;i++){
    const int r = r8 + i*8;
    t[r][c] = src[(size_t)(k0+r)*N + n0 + c];
  }
  __syncthreads();
  #pragma unroll
  for (int i=0;i<4;i++){
    const int r = r8 + i*8;
    dst[(size_t)(n0+r)*K + k0 + c] = f2bs(t[c][r]);
  }
}

// ---------------- RMSNorm (f32 in -> bf16 out, f32 weights) ----------------
__global__ __launch_bounds__(256) void rmsnorm_kernel(
    const float* __restrict__ x, const float* __restrict__ w, bf16* __restrict__ out)
{
  const int row = blockIdx.x;
  const float* xr = x + (size_t)row*Dz;
  const int i0 = threadIdx.x*4;
  float4 xv = *(const float4*)(xr + i0);
  float ss = xv.x*xv.x+xv.y*xv.y+xv.z*xv.z+xv.w*xv.w;
  #pragma unroll
  for (int off=32; off>=1; off>>=1) ss += __shfl_xor(ss, off);
  __shared__ float red[4];
  if ((threadIdx.x&63)==0) red[threadIdx.x>>6] = ss;
  __syncthreads();
  ss = red[0]+red[1]+red[2]+red[3];
  const float inv = rsqrtf(ss*(1.f/Dz) + 1e-6f);
  float4 wv = *(const float4*)(w + i0);
  ushort4 ov;
  ov.x=f2bs(xv.x*inv*wv.x); ov.y=f2bs(xv.y*inv*wv.y);
  ov.z=f2bs(xv.z*inv*wv.z); ov.w=f2bs(xv.w*inv*wv.w);
  *(ushort4*)((us*)out + (size_t)row*Dz + i0) = ov;
}

// ------------- MFMA GEMM: C[M,N] = A[M,K](bf16) @ BT[N,K](bf16)^T (+res) -------------
// XCD-aware swizzle: grids must have (gridX*gridY)%8==0 (all call sites satisfy).
// MODE 0: write bf16.  MODE 1: write f32 + f32 residual.
template<int MODE>
__global__ __launch_bounds__(256, 2) void mgemm_kernel(
    const bf16* __restrict__ A, const us* __restrict__ BT,
    const void* __restrict__ res, void* __restrict__ Cout,
    int M, int N, int K)
{
  __shared__ us As[128*64];
  __shared__ us Bs[128*64];
  const int nwgx = gridDim.x;
  const int lid = blockIdx.y*nwgx + blockIdx.x;
  const int cpx = (nwgx*gridDim.y) >> 3;
  const int swz = (lid & 7)*cpx + (lid >> 3);
  const int m0 = (swz / nwgx)*128, n0 = (swz % nwgx)*128;
  const int tid = threadIdx.x;
  const int wid = tid >> 6, lane = tid & 63;
  const int wr = wid >> 1, wc = wid & 1;
  const int fq = lane >> 4, fr = lane & 15;

  const us* Ab = (const us*)A + (size_t)(m0 + (tid>>3))*K + (tid&7)*8;
  const us* Bb = BT + (size_t)(n0 + (tid>>3))*K + (tid&7)*8;
  char* AsB = (char*)As;
  char* BsB = (char*)Bs;
  const int ldsoff = wid*1024;

  f32x4 acc[4][4] = {};
  const int nk = K >> 6;
  for (int kt = 0; kt < nk; ++kt){
    const int kb = kt*64;
    #pragma unroll
    for (int i=0;i<4;i++){
      GLOAD16(Ab + (size_t)(32*i)*K + kb, AsB + ldsoff + i*4096);
      GLOAD16(Bb + (size_t)(32*i)*K + kb, BsB + ldsoff + i*4096);
    }
    __syncthreads();
    #pragma unroll
    for (int ks=0; ks<2; ks++){
      short8v af[4], bf[4];
      #pragma unroll
      for (int r=0;r<4;r++)
        af[r] = *(const short8v*)&As[(wr*64 + r*16 + fr)*64 + ks*32 + fq*8];
      #pragma unroll
      for (int c=0;c<4;c++)
        bf[c] = *(const short8v*)&Bs[(wc*64 + c*16 + fr)*64 + ks*32 + fq*8];
      #pragma unroll
      for (int r=0;r<4;r++)
        #pragma unroll
        for (int c=0;c<4;c++)
          acc[r][c] = __builtin_amdgcn_mfma_f32_16x16x32_bf16(af[r], bf[c], acc[r][c], 0, 0, 0);
    }
    __syncthreads();
  }
  #pragma unroll
  for (int r=0;r<4;r++){
    #pragma unroll
    for (int c=0;c<4;c++){
      const int col = n0 + wc*64 + c*16 + fr;
      #pragma unroll
      for (int jj=0;jj<4;jj++){
        const int row = m0 + wr*64 + r*16 + fq*4 + jj;
        const size_t idx = (size_t)row*N + col;
        const float a = acc[r][c][jj];
        if (MODE==0){
          ((us*)Cout)[idx] = f2bs(a);
        } else {
          ((float*)Cout)[idx] = a + ((const float*)res)[idx];
        }
      }
    }
  }
}

// ------- merged QKVG projection GEMM: A[M,1024] @ qkvgT[4608,1024]^T -------
__global__ __launch_bounds__(256, 2) void proj_gemm_kernel(
    const bf16* __restrict__ A, const us* __restrict__ BT,
    us* __restrict__ preq, us* __restrict__ prek,
    us* __restrict__ prev, us* __restrict__ gout,
    int M, int N, int K)
{
  __shared__ us As[128*64];
  __shared__ us Bs[128*64];
  const int nwgx = gridDim.x;
  const int lid = blockIdx.y*nwgx + blockIdx.x;
  const int cpx = (nwgx*gridDim.y) >> 3;
  const int swz = (lid & 7)*cpx + (lid >> 3);
  const int m0 = (swz / nwgx)*128, n0 = (swz % nwgx)*128;
  const int tid = threadIdx.x;
  const int wid = tid >> 6, lane = tid & 63;
  const int wr = wid >> 1, wc = wid & 1;
  const int fq = lane >> 4, fr = lane & 15;

  const us* Ab = (const us*)A + (size_t)(m0 + (tid>>3))*K + (tid&7)*8;
  const us* Bb = BT + (size_t)(n0 + (tid>>3))*K + (tid&7)*8;
  char* AsB = (char*)As;
  char* BsB = (char*)Bs;
  const int ldsoff = wid*1024;

  f32x4 acc[4][4] = {};
  const int nk = K >> 6;
  for (int kt = 0; kt < nk; ++kt){
    const int kb = kt*64;
    #pragma unroll
    for (int i=0;i<4;i++){
      GLOAD16(Ab + (size_t)(32*i)*K + kb, AsB + ldsoff + i*4096);
      GLOAD16(Bb + (size_t)(32*i)*K + kb, BsB + ldsoff + i*4096);
    }
    __syncthreads();
    #pragma unroll
    for (int ks=0; ks<2; ks++){
      short8v af[4], bf[4];
      #pragma unroll
      for (int r=0;r<4;r++)
        af[r] = *(const short8v*)&As[(wr*64 + r*16 + fr)*64 + ks*32 + fq*8];
      #pragma unroll
      for (int c=0;c<4;c++)
        bf[c] = *(const short8v*)&Bs[(wc*64 + c*16 + fr)*64 + ks*32 + fq*8];
      #pragma unroll
      for (int r=0;r<4;r++)
        #pragma unroll
        for (int c=0;c<4;c++)
          acc[r][c] = __builtin_amdgcn_mfma_f32_16x16x32_bf16(af[r], bf[c], acc[r][c], 0, 0, 0);
    }
    __syncthreads();
  }
  // block-uniform scatter target (col tiles align to 768/1536/3072 boundaries)
  us* dst; int col0, Nout;
  if (n0 < 768)      { dst = preq; col0 = n0;        Nout = 768;  }
  else if (n0 < 1536){ dst = prek; col0 = n0 - 768;  Nout = 768;  }
  else if (n0 < 3072){ dst = prev; col0 = n0 - 1536; Nout = 1536; }
  else               { dst = gout; col0 = n0 - 3072; Nout = 1536; }
  #pragma unroll
  for (int r=0;r<4;r++){
    #pragma unroll
    for (int c=0;c<4;c++){
      const int col = col0 + wc*64 + c*16 + fr;
      #pragma unroll
      for (int jj=0;jj<4;jj++){
        const int row = m0 + wr*64 + r*16 + fq*4 + jj;
        dst[(size_t)row*Nout + col] = f2bs(acc[r][c][jj]);
      }
    }
  }
}

// ------- fused dual GEMM: out = silu(A@Wg^T) * (A@Wu^T), bf16 -------
__global__ __launch_bounds__(256, 2) void mgemm_dual_kernel(
    const bf16* __restrict__ A, const us* __restrict__ BT1, const us* __restrict__ BT2,
    us* __restrict__ Cout, int M, int N, int K)
{
  __shared__ us As[128*64];
  __shared__ us Bs1[128*64];
  __shared__ us Bs2[128*64];
  const int nwgx = gridDim.x;
  const int lid = blockIdx.y*nwgx + blockIdx.x;
  const int cpx = (nwgx*gridDim.y) >> 3;
  const int swz = (lid & 7)*cpx + (lid >> 3);
  const int m0 = (swz / nwgx)*128, n0 = (swz % nwgx)*128;
  const int tid = threadIdx.x;
  const int wid = tid >> 6, lane = tid & 63;
  const int wr = wid >> 1, wc = wid & 1;
  const int fq = lane >> 4, fr = lane & 15;

  const us* Ab  = (const us*)A + (size_t)(m0 + (tid>>3))*K + (tid&7)*8;
  const us* Bb1 = BT1 + (size_t)(n0 + (tid>>3))*K + (tid&7)*8;
  const us* Bb2 = BT2 + (size_t)(n0 + (tid>>3))*K + (tid&7)*8;
  char* AsB  = (char*)As;
  char* BsB1 = (char*)Bs1;
  char* BsB2 = (char*)Bs2;
  const int ldsoff = wid*1024;

  f32x4 acc1[4][4] = {};
  f32x4 acc2[4][4] = {};
  const int nk = K >> 6;
  for (int kt = 0; kt < nk; ++kt){
    const int kb = kt*64;
    #pragma unroll
    for (int i=0;i<4;i++){
      GLOAD16(Ab  + (size_t)(32*i)*K + kb, AsB  + ldsoff + i*4096);
      GLOAD16(Bb1 + (size_t)(32*i)*K + kb, BsB1 + ldsoff + i*4096);
      GLOAD16(Bb2 + (size_t)(32*i)*K + kb, BsB2 + ldsoff + i*4096);
    }
    __syncthreads();
    #pragma unroll
    for (int ks=0; ks<2; ks++){
      short8v af[4], bf1[4], bf2[4];
      #pragma unroll
      for (int r=0;r<4;r++)
        af[r] = *(const short8v*)&As[(wr*64 + r*16 + fr)*64 + ks*32 + fq*8];
      #pragma unroll
      for (int c=0;c<4;c++){
        bf1[c] = *(const short8v*)&Bs1[(wc*64 + c*16 + fr)*64 + ks*32 + fq*8];
        bf2[c] = *(const short8v*)&Bs2[(wc*64 + c*16 + fr)*64 + ks*32 + fq*8];
      }
      #pragma unroll
      for (int r=0;r<4;r++)
        #pragma unroll
        for (int c=0;c<4;c++){
          acc1[r][c] = __builtin_amdgcn_mfma_f32_16x16x32_bf16(af[r], bf1[c], acc1[r][c], 0, 0, 0);
          acc2[r][c] = __builtin_amdgcn_mfma_f32_16x16x32_bf16(af[r], bf2[c], acc2[r][c], 0, 0, 0);
        }
    }
    __syncthreads();
  }
  #pragma unroll
  for (int r=0;r<4;r++){
    #pragma unroll
    for (int c=0;c<4;c++){
      const int col = n0 + wc*64 + c*16 + fr;
      #pragma unroll
      for (int jj=0;jj<4;jj++){
        const int row = m0 + wr*64 + r*16 + fq*4 + jj;
        Cout[(size_t)row*N + col] = f2bs(siluf_(acc1[r][c][jj]) * acc2[r][c][jj]);
      }
    }
  }
}

// ------- beta / exp(g) projections -> meta = (exp(g), beta) float2 -------
__global__ __launch_bounds__(256) void beta_g_kernel(
    const bf16* __restrict__ hh, const float* __restrict__ Wb, const float* __restrict__ Wa,
    const float* __restrict__ A_log, const float* __restrict__ dt_bias,
    float2* __restrict__ meta)
{
  const int row = blockIdx.x;
  const us* hr = (const us*)hh + (size_t)row*Dz;
  float ab[8]={0,0,0,0,0,0,0,0}, aa[8]={0,0,0,0,0,0,0,0};
  for (int kk=threadIdx.x; kk<Dz; kk+=256){
    const float hv = us2f(hr[kk]);
    float4 b0 = *(const float4*)(Wb + kk*8);
    float4 b1 = *(const float4*)(Wb + kk*8 + 4);
    float4 a0 = *(const float4*)(Wa + kk*8);
    float4 a1 = *(const float4*)(Wa + kk*8 + 4);
    ab[0]=fmaf(hv,b0.x,ab[0]); ab[1]=fmaf(hv,b0.y,ab[1]);
    ab[2]=fmaf(hv,b0.z,ab[2]); ab[3]=fmaf(hv,b0.w,ab[3]);
    ab[4]=fmaf(hv,b1.x,ab[4]); ab[5]=fmaf(hv,b1.y,ab[5]);
    ab[6]=fmaf(hv,b1.z,ab[6]); ab[7]=fmaf(hv,b1.w,ab[7]);
    aa[0]=fmaf(hv,a0.x,aa[0]); aa[1]=fmaf(hv,a0.y,aa[1]);
    aa[2]=fmaf(hv,a0.z,aa[2]); aa[3]=fmaf(hv,a0.w,aa[3]);
    aa[4]=fmaf(hv,a1.x,aa[4]); aa[5]=fmaf(hv,a1.y,aa[5]);
    aa[6]=fmaf(hv,a1.z,aa[6]); aa[7]=fmaf(hv,a1.w,aa[7]);
  }
  #pragma unroll
  for (int off=32; off>=1; off>>=1){
    #pragma unroll
    for (int n=0;n<8;n++){ ab[n]+=__shfl_xor(ab[n],off); aa[n]+=__shfl_xor(aa[n],off); }
  }
  __shared__ float red[4][16];
  const int wv = threadIdx.x>>6, ln = threadIdx.x&63;
  if (ln==0){
    #pragma unroll
    for (int n=0;n<8;n++){ red[wv][n]=ab[n]; red[wv][8+n]=aa[n]; }
  }
  __syncthreads();
  if (threadIdx.x < 8){
    const int n = threadIdx.x;
    float sb = red[0][n]+red[1][n]+red[2][n]+red[3][n];
    float sa = red[0][8+n]+red[1][8+n]+red[2][8+n]+red[3][8+n];
    float xx = sa + dt_bias[n];
    float sp = (xx > 20.f) ? xx : log1pf(expf(xx));
    float eg = expf(-expf(A_log[n])*sp);
    float bt = 1.f/(1.f+expf(-sb));
    meta[(size_t)row*Hz + n] = make_float2(eg, bt);
  }
}

// ------- fused conv(K=4)+SiLU+l2norm+scale for k,q -> kqn[bt][h][96k|96q] bf16 -------
// 256 threads = 4 waves; wave w handles unit (bt,h) = blockIdx.x*4 + w.
__global__ __launch_bounds__(256) void conv_kq_kernel(
    const bf16* __restrict__ preq, const bf16* __restrict__ prek,
    const float* __restrict__ wqc, const float* __restrict__ wkc,
    us* __restrict__ kqn)
{
  const int u = blockIdx.x*4 + (threadIdx.x >> 6);
  const int h = u & 7; const int bt = u >> 3;
  const int t = bt & (Tz-1);
  const int lane = threadIdx.x & 63;
  const us* Q = (const us*)preq;
  const us* K = (const us*)prek;
  const int c0 = h*DKz + lane, c1 = c0 + 64;
  const bool hi = lane < 32;
  float yq0=0.f, yq1=0.f, yk0=0.f, yk1=0.f;
  #pragma unroll
  for (int i=0;i<4;i++){
    const int ti = t - 3 + i;
    if (ti >= 0){
      const size_t rowb = (size_t)(bt-3+i)*KDz;
      yq0 = fmaf(us2f(Q[rowb + c0]), wqc[c0*4+i], yq0);
      yk0 = fmaf(us2f(K[rowb + c0]), wkc[c0*4+i], yk0);
      if (hi){
        yq1 = fmaf(us2f(Q[rowb + c1]), wqc[c1*4+i], yq1);
        yk1 = fmaf(us2f(K[rowb + c1]), wkc[c1*4+i], yk1);
      }
    }
  }
  yq0 = siluf_(yq0); yk0 = siluf_(yk0);
  yq1 = hi ? siluf_(yq1) : 0.f;
  yk1 = hi ? siluf_(yk1) : 0.f;
  float ssq = yq0*yq0 + yq1*yq1;
  float ssk = yk0*yk0 + yk1*yk1;
  #pragma unroll
  for (int off=32; off>=1; off>>=1){ ssq += __shfl_xor(ssq,off); ssk += __shfl_xor(ssk,off); }
  const float iq = rsqrtf(ssq + 1e-6f) * 0.10206207262f;  // invq * dk^-0.5
  const float ik = rsqrtf(ssk + 1e-6f);
  const size_t base = (size_t)bt*1536 + (size_t)h*192;
  kqn[base + lane]      = f2bs(yk0*ik);
  kqn[base + 96 + lane] = f2bs(yq0*iq);
  if (hi){
    kqn[base + 64 + lane]      = f2bs(yk1*ik);
    kqn[base + 96 + 64 + lane] = f2bs(yq1*iq);
  }
}

// ------- apply conv+SiLU to v -> vn bf16 -------
__global__ __launch_bounds__(256) void conv_apply_v_kernel(
    const bf16* __restrict__ prev, const float* __restrict__ wvc, bf16* __restrict__ vn)
{
  const int bt = blockIdx.y; const int ccol = blockIdx.x*256 + threadIdx.x;
  const int t = bt & (Tz-1);
  const us* X = (const us*)prev;
  float acc = 0.f;
  #pragma unroll
  for (int i=0;i<4;i++){
    const int ti = t - 3 + i;
    if (ti >= 0) acc = fmaf(us2f(X[(size_t)(bt-3+i)*VDz + ccol]), wvc[ccol*4+i], acc);
  }
  ((us*)vn)[(size_t)bt*VDz + ccol] = f2bs(siluf_(acc));
}

// ---------------- gated delta-rule scan, consume-only, 16-way split ----------------
// Grid = Bz*Hz*16; block (bh, sp) owns v-cols [sp*12, sp*12+12).
// 192 threads: tid = j*16 + g; thread owns S[g*6 .. g*6+5][col sp*12+j].
// 2 blocks/CU -> 6 waves/CU for stall overlap.
// Phase = 16 steps (barriers halved vs 8-step; prefetch wait amortized 2x).
__global__ __launch_bounds__(192, 1) void scan_kernel(
    const us* __restrict__ kqn, const bf16* __restrict__ vn,
    const float2* __restrict__ meta, bf16* __restrict__ o)
{
  const int blk = blockIdx.x;
  const int bh = blk >> 4, sp = blk & 15;
  const int b = bh >> 3, h = bh & 7;
  const int tid = threadIdx.x;
  const int g = tid & 15;
  const int j = tid >> 4;               // 0..11
  const int vc = h*DVz + sp*12 + j;

  __shared__ float kq[2][16][192];      // [buf][step][96 k | 96 q]

  const us* KQ = kqn + (size_t)b*Tz*1536 + h*192 + tid;
  const us* VP = (const us*)vn + (size_t)b*Tz*VDz + vc;
  us* op = (us*)o + (size_t)b*Tz*VDz + vc;
  const float2* MP = meta + (size_t)b*Tz*Hz + h;

  float S[6];
  #pragma unroll
  for (int m=0;m<6;m++) S[m]=0.f;

  float ced[16], egb[16], cvb[16];   // eg, eg*beta, v*beta

  // ---- prologue: stage phase 0 ----
  #pragma unroll
  for (int s=0;s<16;s++){
    kq[0][s][tid] = us2f(KQ[(size_t)s*1536]);
    const float cv = us2f(VP[(size_t)s*VDz]);
    const float2 m = MP[(size_t)s*Hz];
    ced[s] = m.x; egb[s] = m.x*m.y; cvb[s] = cv*m.y;
  }
  __syncthreads();

  for (int ph=0; ph<Tz/16; ph++){
    const int base = ph*16;
    const int p = ph & 1;
    const bool more = (base + 16 < Tz);
    const int nb = more ? base + 16 : base;   // clamp; values unused when !more
    // (1) prefetch next-phase inputs (independent -> issue at top)
    float nkq[16], nv[16]; float2 nm[16];
    #pragma unroll
    for (int s=0;s<16;s++){
      nkq[s] = us2f(KQ[(size_t)(nb+s)*1536]);
      nv[s]  = us2f(VP[(size_t)(nb+s)*VDz]);
      nm[s]  = MP[(size_t)(nb+s)*Hz];
    }
    // (2) consume 16 steps; parity register sets, b64 reads (g*24B: all-banks-once)
    float2 kf[2][3], qf[2][3];
    #pragma unroll
    for (int m=0;m<3;m++){
      kf[0][m] = *(const float2*)&kq[p][0][g*6 + m*2];
      qf[0][m] = *(const float2*)&kq[p][0][96 + g*6 + m*2];
    }
    #pragma unroll
    for (int s=0;s<16;s++){
      const int cu = s & 1, nx = cu ^ 1;
      if (s < 15){
        #pragma unroll
        for (int m=0;m<3;m++){
          kf[nx][m] = *(const float2*)&kq[p][s+1][g*6 + m*2];
          qf[nx][m] = *(const float2*)&kq[p][s+1][96 + g*6 + m*2];
        }
      }
      float a0, a1;
      a0 = kf[cu][0].x*S[0];          a1 = kf[cu][0].y*S[1];
      a0 = fmaf(kf[cu][1].x,S[2],a0); a1 = fmaf(kf[cu][1].y,S[3],a1);
      a0 = fmaf(kf[cu][2].x,S[4],a0); a1 = fmaf(kf[cu][2].y,S[5],a1);
      const float pv = gsum16(a0+a1);
      const float eg = ced[s];
      const float delta = fmaf(-egb[s], pv, cvb[s]);   // (cv - eg*pv)*beta
      float o0, o1, t0;
      t0 = fmaf(eg,S[0], kf[cu][0].x*delta); S[0]=t0; o0 = qf[cu][0].x*t0;
      t0 = fmaf(eg,S[1], kf[cu][0].y*delta); S[1]=t0; o1 = qf[cu][0].y*t0;
      t0 = fmaf(eg,S[2], kf[cu][1].x*delta); S[2]=t0; o0 = fmaf(qf[cu][1].x,t0,o0);
      t0 = fmaf(eg,S[3], kf[cu][1].y*delta); S[3]=t0; o1 = fmaf(qf[cu][1].y,t0,o1);
      t0 = fmaf(eg,S[4], kf[cu][2].x*delta); S[4]=t0; o0 = fmaf(qf[cu][2].x,t0,o0);
      t0 = fmaf(eg,S[5], kf[cu][2].y*delta); S[5]=t0; o1 = fmaf(qf[cu][2].y,t0,o1);
      const float po = gsum16(o0+o1);
      if (g == 0) op[(size_t)(base+s)*VDz] = f2bs(po);
    }
    // (3) stage next phase from prefetched registers (1:1, branch-free)
    if (more){
      #pragma unroll
      for (int s=0;s<16;s++){
        kq[p^1][s][tid] = nkq[s];
        ced[s] = nm[s].x; egb[s] = nm[s].x*nm[s].y; cvb[s] = nv[s]*nm[s].y;
      }
    }
    __syncthreads();
  }
}

// ---------------- output gate: rmsnorm_dv(o) * silu(gout) ----------------
// 256 threads = 4 waves; wave w handles row blockIdx.x*4 + w.
__global__ __launch_bounds__(256) void gate_out_kernel(
    const bf16* __restrict__ o, const bf16* __restrict__ gout,
    const float* __restrict__ onw, bf16* __restrict__ og)
{
  const int row = blockIdx.x*4 + (threadIdx.x >> 6);
  const size_t base = (size_t)row * DVz;
  const int lane = threadIdx.x & 63;
  const us* O = (const us*)o;
  float x0 = us2f(O[base+lane]), x1 = us2f(O[base+64+lane]), x2 = us2f(O[base+128+lane]);
  float ss = x0*x0 + x1*x1 + x2*x2;
  #pragma unroll
  for (int off=32; off>=1; off>>=1) ss += __shfl_xor(ss, off);
  const float inv = rsqrtf(ss*(1.f/DVz) + 1e-6f);
  const us* G = (const us*)gout;
  us* OG = (us*)og;
  float xs[3] = {x0, x1, x2};
  #pragma unroll
  for (int i=0;i<3;i++){
    const int c = lane + 64*i;
    const float gv = us2f(G[base+c]);
    OG[base+c] = f2bs(xs[i]*inv*onw[c] * siluf_(gv));
  }
}

extern "C" void kernel_launch(void* const* d_in, const int* in_sizes, int n_in,
                              void* d_out, int out_size, void* d_ws, size_t ws_size,
                              hipStream_t stream) {
  const float* x        = (const float*)d_in[0];
  const float* Wq       = (const float*)d_in[1];
  const float* Wk       = (const float*)d_in[2];
  const float* Wv       = (const float*)d_in[3];
  const float* Wb       = (const float*)d_in[4];
  const float* Wa       = (const float*)d_in[5];
  const float* A_log    = (const float*)d_in[6];
  const float* dt_bias  = (const float*)d_in[7];
  const float* conv_q_w = (const float*)d_in[8];
  const float* conv_k_w = (const float*)d_in[9];
  const float* conv_v_w = (const float*)d_in[10];
  const float* Wg       = (const float*)d_in[11];
  const float* onorm_w  = (const float*)d_in[12];
  const float* Wo       = (const float*)d_in[13];
  const float* norm1_w  = (const float*)d_in[14];
  const float* norm2_w  = (const float*)d_in[15];
  const float* Wgate    = (const float*)d_in[16];
  const float* Wup      = (const float*)d_in[17];
  const float* Wdown    = (const float*)d_in[18];

  char* W = (char*)d_ws;
  // bf16-transposed weights (rewritten every launch; deterministic)
  us* WoT    = (us*)(W + 0);           // live thru Wo GEMM
  us* WgateT = (us*)(W + 3145728);     // live thru MLP
  us* WupT   = (us*)(W + 11534336);
  us* WdownT = (us*)(W + 19922944);    // ends 28,311,552
  // concatenated qkvg^T [4608,1024] bf16 (q rows 0-767, k 768-1535, v 1536-3071,
  // g 3072-4607); dead after proj GEMM
  us* WqkvgT = (us*)(W + 28311552);    // ends 37,748,736
  // activations
  bf16*   h_   = (bf16*)  (W + 37748736);   // [8192,1024]; dead after proj GEMM
  bf16*   preq = (bf16*)  (W + 54525952);   // [8192,768];  dead after conv_kq
  bf16*   prek = (bf16*)  (W + 67108864);   // [8192,768];  dead after conv_kq
  bf16*   prev = (bf16*)  (W + 79691776);   // [8192,1536]; dead after conv_apply_v
  float2* meta = (float2*)(W + 104857600);  // [8192,8] float2; dead after scan
  bf16*   gout = (bf16*)  (W + 105906176);  // [8192,1536]; ends 131,072,000 (PEAK)
  // aliases over dead regions
  us*    kqn   = (us*)   (W + 28311552);   // [8192,1536] bf16 over WqkvgT+h_-head (dead after scan)
  bf16*  vn    = (bf16*) (W + 54525952);   // [8192,1536] over preq+prek (dead after scan)
  bf16*  o_    = (bf16*) (W + 79691776);   // [8192,1536] over prev (dead after gate_out)
  float* x2    = (float*)(W + 79691776);   // [8192,1024] f32 over o_+meta+gout-head (post gate_out)
  bf16*  og    = (bf16*) (W + 28311552);   // [8192,1536] over kqn (dead after Wo GEMM)
  bf16*  h2    = (bf16*) (W + 113246208);  // [8192,1024] over gout tail (dead after gate_out)
  bf16*  gateC = (bf16*) (W + 28311552);   // [4096,4096] over og+vn region (dead after Wo GEMM)

  // 0. weight prep (transpose + f32->bf16), single merged launch (18432 tiles)
  wprep_all_kernel<<<18432, 256, 0, stream>>>(
      Wo, Wgate, Wup, Wdown, Wq, Wk, Wv, Wg,
      WoT, WgateT, WupT, WdownT,
      WqkvgT, WqkvgT + 768*1024, WqkvgT + 1536*1024, WqkvgT + 3072*1024);
  // 1. pre-norm
  rmsnorm_kernel<<<BTz, 256, 0, stream>>>(x, norm1_w, h_);
  // 2. merged q/k/v/g projection (one GEMM, scatter epilogue) + meta
  proj_gemm_kernel<<<dim3(36,64), 256, 0, stream>>>(h_, WqkvgT,
      (us*)preq, (us*)prek, (us*)prev, (us*)gout, BTz, 4608, Dz);
  beta_g_kernel<<<BTz, 256, 0, stream>>>(h_, Wb, Wa, A_log, dt_bias, meta);
  // 3. fused conv+silu+l2+scale -> kqn; conv+silu -> vn; consume-only scan
  conv_kq_kernel<<<BTz*Hz/4, 256, 0, stream>>>(preq, prek, conv_q_w, conv_k_w, kqn);
  conv_apply_v_kernel<<<dim3(6, BTz), 256, 0, stream>>>(prev, conv_v_w, vn);
  scan_kernel<<<Bz*Hz*16, 192, 0, stream>>>(kqn, vn, meta, o_);
  // 4. output gating + Wo projection with residual
  gate_out_kernel<<<BTz*Hz/4, 256, 0, stream>>>(o_, gout, onorm_w, og);
  mgemm_kernel<1><<<dim3(8,64), 256, 0, stream>>>(og, WoT, x, x2, BTz, Dz, VDz);
  // 5. MLP, chunked over 2 x 4096 rows; gate&up fused into one dual GEMM
  rmsnorm_kernel<<<BTz, 256, 0, stream>>>(x2, norm2_w, h2);
  for (int c = 0; c < 2; c++){
    const bf16*  h2c = h2 + (size_t)c*4096*Dz;
    const float* x2c = x2 + (size_t)c*4096*Dz;
    float*       out = (float*)d_out + (size_t)c*4096*Dz;
    mgemm_dual_kernel<<<dim3(32,32), 256, 0, stream>>>(h2c, WgateT, WupT, (us*)gateC,
                                                       4096, Iz, Dz);
    mgemm_kernel<1><<<dim3(8,32),  256, 0, stream>>>(gateC, WdownT, x2c, out, 4096, Dz, Iz);
  }
}